// Round 10
// baseline (440.095 us; speedup 1.0000x reference)
//
#include <hip/hip_runtime.h>
#include <cstdint>
#include <cstddef>

typedef unsigned short u16;
typedef unsigned int u32;

#define L_TOK 16384
#define DMODEL 256
#define NHEAD 8
#define HDIM 32

typedef __attribute__((ext_vector_type(8))) short bf16x8;
typedef __attribute__((ext_vector_type(4))) float f32x4;
typedef __attribute__((ext_vector_type(4))) unsigned short u16x4;

__device__ __forceinline__ float bf2f(u16 u) {
    union { unsigned int i; float f; } v; v.i = ((unsigned int)u) << 16; return v.f;
}
__device__ __forceinline__ u16 f2bf(float f) {
    union { unsigned int i; float f; } v; v.f = f;
    unsigned int i = v.i;
    unsigned int r = (i + 0x7FFFu + ((i >> 16) & 1u)) >> 16;
    return (u16)r;
}

// direct global->LDS DMA, 16B per lane; LDS dest is wave-uniform base + lane*16
__device__ __forceinline__ void gload16(const u16* g, u16* l) {
    __builtin_amdgcn_global_load_lds((const __attribute__((address_space(1))) u32*)g,
                                     (__attribute__((address_space(3))) u32*)l, 16, 0, 0);
}

// ---------------- sentinel fill (FLOAT output) ----------------
__global__ __launch_bounds__(256) void fill_kernel(float* __restrict__ out, int n, float v) {
    int t = blockIdx.x * 256 + threadIdx.x;
    if (t < n) out[t] = v;
}

// ---------------- tiled transpose: out[l][d](bf16) = in[d][l](f32), coalesced both sides
__global__ __launch_bounds__(256) void xpose_tiled(const float* __restrict__ in,
                                                   u16* __restrict__ out) {
    __shared__ float t[64][65];
    int d0 = blockIdx.x * 64, l0 = blockIdx.y * 64;
    int c = threadIdx.x & 63, r4 = threadIdx.x >> 6;
#pragma unroll
    for (int it = 0; it < 16; ++it) {
        int r = it * 4 + r4;
        t[r][c] = in[(size_t)(d0 + r) * L_TOK + l0 + c];
    }
    __syncthreads();
#pragma unroll
    for (int it = 0; it < 16; ++it) {
        int r = it * 4 + r4;
        out[(size_t)(l0 + r) * DMODEL + d0 + c] = f2bf(t[c][r]);
    }
}

// ---------------- q[l][d] = x[l][d] + pos[d][l], tiled (pos stays f32) ----------------
__global__ __launch_bounds__(256) void addq_tiled(const u16* __restrict__ x,
                                                  const float* __restrict__ p,
                                                  u16* __restrict__ q) {
    __shared__ float t[64][65];
    int d0 = blockIdx.x * 64, l0 = blockIdx.y * 64;
    int c = threadIdx.x & 63, r4 = threadIdx.x >> 6;
#pragma unroll
    for (int it = 0; it < 16; ++it) {
        int r = it * 4 + r4;
        t[r][c] = p[(size_t)(d0 + r) * L_TOK + l0 + c];
    }
    __syncthreads();
#pragma unroll
    for (int it = 0; it < 16; ++it) {
        int r = it * 4 + r4;
        size_t idx = (size_t)(l0 + r) * DMODEL + d0 + c;
        q[idx] = f2bf(bf2f(x[idx]) + t[c][r]);
    }
}

// ---------------- ONE prepack kernel for all weights, both layers ----------------
// per-layer u16 offsets in wbuf (layer stride 1474560):
//   comb_hi 0 / comb_lo 65536 / comb_bias(f32) 131072   (attn cols 0..199, box 200..231)
//   v 163840/229376   o 294912/360448   w1 425984/688128   w2 950272/1212416
__global__ __launch_bounds__(256) void prepack_all(const float* __restrict__ Wattn,
                                                   const float* __restrict__ Wbox,
                                                   const float* __restrict__ battn,
                                                   const float* __restrict__ bbox,
                                                   const float* __restrict__ Wv,
                                                   const float* __restrict__ Wo,
                                                   const float* __restrict__ W1,
                                                   const float* __restrict__ W2,
                                                   u16* __restrict__ wbuf) {
    const int PER_LAYER = 720896;   // 3*65536 + 2*262144
    int idx = blockIdx.x * 256 + threadIdx.x;
    if (idx >= 2 * PER_LAYER) return;
    int layer = idx / PER_LAYER;
    int r = idx - layer * PER_LAYER;
    u16* wb = wbuf + (size_t)layer * 1474560;
    float w; u16* hi; u16* lo; int pos;
    if (r < 65536) {                       // combined attn+box [256n][256k]
        int n = r >> 8, k = r & 255;
        const float* Wa = Wattn + (size_t)layer * 51200;
        const float* Wb = Wbox  + (size_t)layer * 8192;
        w = (n < 200) ? Wa[(size_t)k * 200 + n]
                      : (n < 232 ? Wb[(size_t)k * 32 + (n - 200)] : 0.f);
        hi = wb; lo = wb + 65536; pos = r;
        if (k == 0) {
            float* bias = (float*)(wb + 131072);
            bias[n] = (n < 200) ? battn[layer * 200 + n]
                                : (n < 232 ? bbox[layer * 32 + n - 200] : 0.f);
        }
    } else if (r < 131072) {               // Wv [256n][256k]
        int rr = r - 65536; int n = rr >> 8, k = rr & 255;
        w = Wv[(size_t)layer * 65536 + (size_t)k * 256 + n];
        hi = wb + 163840; lo = wb + 229376; pos = rr;
    } else if (r < 196608) {               // Wo [256n][256k]
        int rr = r - 131072; int n = rr >> 8, k = rr & 255;
        w = Wo[(size_t)layer * 65536 + (size_t)k * 256 + n];
        hi = wb + 294912; lo = wb + 360448; pos = rr;
    } else if (r < 458752) {               // W1 [1024n][256k]
        int rr = r - 196608; int n = rr >> 8, k = rr & 255;
        w = W1[(size_t)layer * 262144 + (size_t)k * 1024 + n];
        hi = wb + 425984; lo = wb + 688128; pos = rr;
    } else {                               // W2 [256n][1024k]
        int rr = r - 458752; int n = rr >> 10, k = rr & 1023;
        w = W2[(size_t)layer * 262144 + (size_t)k * 256 + n];
        hi = wb + 950272; lo = wb + 1212416; pos = rr;
    }
    u16 h = f2bf(w);
    hi[pos] = h;
    lo[pos] = f2bf(w - bf2f(h));
}

// ---------------- MFMA GEMM (dual): 2-phase dbuf + XOR swizzle + XCD swizzle ----
#define BN 64
#define BK 64

template<int BMv>
__global__ __launch_bounds__(256) void gemm_dual(const u16* __restrict__ Aa,
                                                 const u16* __restrict__ Bha,
                                                 const u16* __restrict__ Bla,
                                                 const float* __restrict__ biasa,
                                                 u16* __restrict__ Ca,
                                                 const u16* __restrict__ Ab,
                                                 const u16* __restrict__ Bhb,
                                                 const u16* __restrict__ Blb,
                                                 const float* __restrict__ biasb,
                                                 u16* __restrict__ Cb,
                                                 int K, int ldC, int relu, int ysplit) {
    constexpr int ASZ = BMv * BK;
    constexpr int BSZ = BN * BK;
    constexpr int ACH = BMv / 32;
    constexpr int NI  = BMv / 32;
    __shared__ __align__(16) u16 lds[2][ASZ + 2 * BSZ];  // BMv=128: 64 KB

    const int tid  = threadIdx.x;
    const int lane = tid & 63;
    const int wave = tid >> 6;
    const int wm = wave >> 1, wn = wave & 1;
    const int row = lane & 15, kch = lane >> 4;

    // XCD-chunked bijective swizzle (T1)
    const int nx = gridDim.x;
    const int nwg = nx * gridDim.y;
    int id = blockIdx.y * nx + blockIdx.x;
    if ((nwg & 7) == 0) { int qq = nwg >> 3; id = (id & 7) * qq + (id >> 3); }
    int by = id / nx;
    const int n0 = (id % nx) * BN;

    // sub-problem select (block-uniform)
    const int sel = by >= ysplit;
    if (sel) by -= ysplit;
    const int m0 = by * BMv;
    const u16*  A    = sel ? Ab    : Aa;
    const u16*  Bhi  = sel ? Bhb   : Bha;
    const u16*  Blo  = sel ? Blb   : Bla;
    const float* bias = sel ? biasb : biasa;
    u16*        C    = sel ? Cb    : Ca;

    // pre-swizzled global source (rule #21): LDS row r, slot s holds global (r, s^(r&7))
    const int srow  = tid >> 3;
    const int sslot = (tid & 7) ^ (srow & 7);
    const u16* ga  = A   + (size_t)(m0 + srow) * K + sslot * 8;
    const u16* gbh = Bhi + (size_t)(n0 + srow) * K + sslot * 8;
    const u16* gbl = Blo + (size_t)(n0 + srow) * K + sslot * 8;

    f32x4 acc[NI][2] = {};
    const int nkt = K / BK;

    auto stage = [&](int kt, int buf) {
        u16* lb = &lds[buf][0];
        const int ko = kt * BK;
#pragma unroll
        for (int it = 0; it < ACH; ++it)
            gload16(ga + ko + (size_t)it * 32 * K, lb + tid * 8 + it * 2048);
#pragma unroll
        for (int it = 0; it < 2; ++it) {
            gload16(gbh + ko + (size_t)it * 32 * K, lb + ASZ + tid * 8 + it * 2048);
            gload16(gbl + ko + (size_t)it * 32 * K, lb + ASZ + BSZ + tid * 8 + it * 2048);
        }
    };

    stage(0, 0);
    __syncthreads();                      // tile 0 ready
    for (int t = 0; t < nkt; ++t) {
        const int cur = t & 1;
        if (t + 1 < nkt) stage(t + 1, cur ^ 1);   // prefetch next tile (other buffer)

        const u16* lb = &lds[cur][0];
#pragma unroll
        for (int kk = 0; kk < 2; ++kk) {
            const int ks = kk * 4 + kch;          // global 16B k-slot 0..7
            bf16x8 af[NI];
#pragma unroll
            for (int i = 0; i < NI; ++i) {
                const int r = wm * (BMv / 2) + i * 16 + row;
                af[i] = *(const bf16x8*)(lb + r * BK + ((ks ^ (r & 7)) * 8));
            }
#pragma unroll
            for (int j = 0; j < 2; ++j) {
                const int rb = wn * 32 + j * 16 + row;
                bf16x8 bh = *(const bf16x8*)(lb + ASZ + rb * BK + ((ks ^ (rb & 7)) * 8));
                bf16x8 bl = *(const bf16x8*)(lb + ASZ + BSZ + rb * BK + ((ks ^ (rb & 7)) * 8));
#pragma unroll
                for (int i = 0; i < NI; ++i) {
                    acc[i][j] = __builtin_amdgcn_mfma_f32_16x16x32_bf16(af[i], bh, acc[i][j], 0, 0, 0);
                    acc[i][j] = __builtin_amdgcn_mfma_f32_16x16x32_bf16(af[i], bl, acc[i][j], 0, 0, 0);
                }
            }
        }
        __syncthreads();   // drains prefetch + joins reads; next buffer ready
    }

    // epilogue: C/D layout col = lane&15, row = (lane>>4)*4 + reg
    const int cm0 = m0 + wm * (BMv / 2) + (lane >> 4) * 4;
    const int cn0 = n0 + wn * 32 + (lane & 15);
#pragma unroll
    for (int j = 0; j < 2; ++j) {
        int cn = cn0 + j * 16;
        float bv_ = bias[cn];
#pragma unroll
        for (int i = 0; i < NI; ++i) {
#pragma unroll
            for (int r = 0; r < 4; ++r) {
                float v = acc[i][j][r] + bv_;
                if (relu) v = fmaxf(v, 0.f);
                C[(size_t)(cm0 + i * 16 + r) * ldC + cn] = f2bf(v);
            }
        }
    }
}

// one thread = (pair, 8-wide hd chunk); FUSED softmax (reads raw scores) +
// interior fast path. ALL 25-iter loops are `#pragma unroll 1` — R7's spill came
// from the compiler pipelining the fully-unrolled loop (~100 live loads, 256 VGPR).
__global__ __launch_bounds__(256) void sample_kernel(const u16* __restrict__ val,
                                                     const u16* __restrict__ awb,
                                                     u16* __restrict__ out) {
    int tid = blockIdx.x * 256 + threadIdx.x;
    int ch = tid & 3;             // hd chunk (8 elems)
    int pair = tid >> 2;          // l*NH + n
    int n = pair & 7;
    int l = pair >> 3;
    int iy = l >> 7, ix = l & 127;
    float cx = (ix + 0.5f) * (1.f / 128.f);
    float cy = (iy + 0.5f) * (1.f / 128.f);
    const u16* rowp = awb + (size_t)l * 256;
    const u16* o = rowp + 200 + n * 4;
    float bx = cx + bf2f(o[0]) * (0.025f / 8.f);
    float by = cy + bf2f(o[1]) * (0.025f / 8.f);
    float bw = 0.025f + bf2f(o[2]) * (0.025f / 8.f);
    float bh = 0.025f + bf2f(o[3]) * (0.025f / 8.f);
    const u16* awp = rowp + n * 25;   // RAW scores (softmax fused here)
    const u16* vbase = val + n * 32 + ch * 8;

    // fused softmax stats: two cheap passes (awp is L1-resident), no v[25] array
    float mx = -1e30f;
#pragma unroll 1
    for (int k = 0; k < 25; k++) mx = fmaxf(mx, bf2f(awp[k]));
    float s = 0.f;
#pragma unroll 1
    for (int k = 0; k < 25; k++) s += __expf(bf2f(awp[k]) - mx);
    float inv = 1.f / s;

    float bx128 = bx * 128.f - 0.5f;
    float by128 = by * 128.f - 0.5f;
    float bwq = bw * 32.f;            // per-grid-step pixel delta
    float bhq = bh * 32.f;
    float ax = 2.f * fabsf(bwq), ay = 2.f * fabsf(bhq);
    bool interior = (bx128 - ax >= 0.f) & (bx128 + ax < 127.f) &
                    (by128 - ay >= 0.f) & (by128 + ay < 127.f);

    float acc[8] = {};
    if (interior) {
#pragma unroll 1
        for (int k = 0; k < 25; k++) {
            float xx = bx128 + (float)(k % 5 - 2) * bwq;
            float yy = by128 + (float)(k / 5 - 2) * bhq;
            float x0 = floorf(xx), y0 = floorf(yy);
            float fx = xx - x0, fy = yy - y0;
            float a_ = __expf(bf2f(awp[k]) - mx) * inv;
            float gx0 = 1.f - fx, gy0 = 1.f - fy;
            float w00 = gx0 * gy0 * a_;
            float w01 = fx * gy0 * a_;
            float w10 = gx0 * fy * a_;
            float w11 = fx * fy * a_;
            const u16* p00 = vbase + ((size_t)((int)y0 * 128 + (int)x0)) * 256;
            bf16x8 v00 = *(const bf16x8*)(p00);
            bf16x8 v01 = *(const bf16x8*)(p00 + 256);
            bf16x8 v10 = *(const bf16x8*)(p00 + 128 * 256);
            bf16x8 v11 = *(const bf16x8*)(p00 + 128 * 256 + 256);
#pragma unroll
            for (int e = 0; e < 8; e++)
                acc[e] += w00 * bf2f((u16)v00[e]) + w01 * bf2f((u16)v01[e]) +
                          w10 * bf2f((u16)v10[e]) + w11 * bf2f((u16)v11[e]);
        }
    } else {
#pragma unroll 1
        for (int k = 0; k < 25; k++) {
            float xx = bx128 + (float)(k % 5 - 2) * bwq;
            float yy = by128 + (float)(k / 5 - 2) * bhq;
            float x0 = floorf(xx), y0 = floorf(yy);
            float a_ = __expf(bf2f(awp[k]) - mx) * inv;
#pragma unroll
            for (int dy = 0; dy < 2; dy++) {
#pragma unroll
                for (int dx = 0; dx < 2; dx++) {
                    float xi = x0 + dx, yi = y0 + dy;
                    float w_ = (1.f - fabsf(xx - xi)) * (1.f - fabsf(yy - yi)) * a_;
                    bool valid = (xi >= 0.f) & (xi < 128.f) & (yi >= 0.f) & (yi < 128.f);
                    w_ = valid ? w_ : 0.f;
                    int ixi = min(max((int)xi, 0), 127);
                    int iyi = min(max((int)yi, 0), 127);
                    int idx = iyi * 128 + ixi;
                    bf16x8 v = *(const bf16x8*)(vbase + (size_t)idx * 256);
#pragma unroll
                    for (int e = 0; e < 8; e++)
                        acc[e] += w_ * bf2f((u16)v[e]);
                }
            }
        }
    }
    bf16x8 ov;
#pragma unroll
    for (int e = 0; e < 8; e++) ov[e] = (short)f2bf(acc[e]);
    *(bf16x8*)(out + (size_t)l * 256 + n * 32 + ch * 8) = ov;
}

// ---------------- LayerNorm: one row per wave, fully in registers ----------------
__global__ __launch_bounds__(256) void ln_rows_bf16(const u16* __restrict__ xin,
                                                    const u16* __restrict__ delta,
                                                    const float* __restrict__ g,
                                                    const float* __restrict__ b,
                                                    u16* __restrict__ out) {
    int lane = threadIdx.x & 63;
    int row = blockIdx.x * 4 + (threadIdx.x >> 6);
    size_t base = (size_t)row * 256 + lane * 4;
    u16x4 xv = *(const u16x4*)(xin + base);
    u16x4 dv = *(const u16x4*)(delta + base);
    float v[4]; float s = 0.f, q = 0.f;
#pragma unroll
    for (int j = 0; j < 4; j++) {
        v[j] = bf2f(xv[j]) + bf2f(dv[j]);
        s += v[j]; q += v[j] * v[j];
    }
#pragma unroll
    for (int off = 1; off < 64; off <<= 1) {
        s += __shfl_xor(s, off, 64);
        q += __shfl_xor(q, off, 64);
    }
    float m = s * (1.f / 256.f);
    float var = q * (1.f / 256.f) - m * m;
    float r = rsqrtf(var + 1e-5f);
    f32x4 gv = *(const f32x4*)(g + lane * 4);
    f32x4 bv2 = *(const f32x4*)(b + lane * 4);
    u16x4 ov;
#pragma unroll
    for (int j = 0; j < 4; j++)
        ov[j] = f2bf((v[j] - m) * r * gv[j] + bv2[j]);
    *(u16x4*)(out + base) = ov;
}

// final LN writes FLOAT32 — d_out is the reference's output dtype (f32)
__global__ __launch_bounds__(256) void ln_rows_f32(const u16* __restrict__ xin,
                                                   const u16* __restrict__ delta,
                                                   const float* __restrict__ g,
                                                   const float* __restrict__ b,
                                                   float* __restrict__ out) {
    int lane = threadIdx.x & 63;
    int row = blockIdx.x * 4 + (threadIdx.x >> 6);
    size_t base = (size_t)row * 256 + lane * 4;
    u16x4 xv = *(const u16x4*)(xin + base);
    u16x4 dv = *(const u16x4*)(delta + base);
    float v[4]; float s = 0.f, q = 0.f;
#pragma unroll
    for (int j = 0; j < 4; j++) {
        v[j] = bf2f(xv[j]) + bf2f(dv[j]);
        s += v[j]; q += v[j] * v[j];
    }
#pragma unroll
    for (int off = 1; off < 64; off <<= 1) {
        s += __shfl_xor(s, off, 64);
        q += __shfl_xor(q, off, 64);
    }
    float m = s * (1.f / 256.f);
    float var = q * (1.f / 256.f) - m * m;
    float r = rsqrtf(var + 1e-5f);
    f32x4 gv = *(const f32x4*)(g + lane * 4);
    f32x4 bv2 = *(const f32x4*)(b + lane * 4);
    f32x4 ov;
#pragma unroll
    for (int j = 0; j < 4; j++)
        ov[j] = (v[j] - m) * r * gv[j] + bv2[j];
    *(f32x4*)(out + base) = ov;
}

extern "C" void kernel_launch(void* const* d_in, const int* in_sizes, int n_in,
                              void* d_out, int out_size, void* d_ws, size_t ws_size,
                              hipStream_t stream) {
    const size_t MiB = 1048576;
    float* outp = (float*)d_out;
    int fillg = (out_size + 255) / 256;

    // ---- environment sentinels ----
    const int exp_sizes[18] = {4194304, 4194304, 131072, 512, 16384, 64, 102400, 400,
                               131072, 512, 524288, 2048, 524288, 512, 512, 512, 512, 512};
    bool env_ok = (n_in == 18) && (ws_size >= 25 * MiB) && (out_size == 4194304);
    if (env_ok) for (int i = 0; i < 18; i++) env_ok = env_ok && (in_sizes[i] == exp_sizes[i]);
    if (!env_ok) {
        hipLaunchKernelGGL(fill_kernel, dim3(fillg), dim3(256), 0, stream, outp, out_size, 3000.f);
        return;
    }

    const float* srcp  = (const float*)d_in[0];
    const float* posp  = (const float*)d_in[1];
    const float* Wv    = (const float*)d_in[2];
    const float* bv    = (const float*)d_in[3];
    const float* Wbox  = (const float*)d_in[4];
    const float* bbox  = (const float*)d_in[5];
    const float* Wattn = (const float*)d_in[6];
    const float* battn = (const float*)d_in[7];
    const float* Wo    = (const float*)d_in[8];
    const float* bo    = (const float*)d_in[9];
    const float* W1    = (const float*)d_in[10];
    const float* b1    = (const float*)d_in[11];
    const float* W2    = (const float*)d_in[12];
    const float* b2    = (const float*)d_in[13];
    const float* ln1g  = (const float*)d_in[14];
    const float* ln1b  = (const float*)d_in[15];
    const float* ln2g  = (const float*)d_in[16];
    const float* ln2b  = (const float*)d_in[17];

    char* ws = (char*)d_ws;
    // ws:   [0,8) x    [8,16) val / hiddenA    [16,24) awb / tmp / ffnout
    // dout: [0,8) q -> attn -> hiddenB (sequential liveness)   [8,~13.6) wbuf
    u16* x       = (u16*)(ws + 0);
    u16* val     = (u16*)(ws + 8 * MiB);
    u16* hiddenA = (u16*)(ws + 8 * MiB);
    u16* awb     = (u16*)(ws + 16 * MiB);
    u16* tmp     = (u16*)(ws + 16 * MiB);
    u16* ffnout  = (u16*)(ws + 16 * MiB);
    u16* q       = (u16*)d_out;
    u16* attn    = (u16*)d_out;
    u16* hiddenB = (u16*)d_out;
    u16* wbuf    = (u16*)((char*)d_out + 8 * MiB);
    const size_t LSTR = 1474560;  // u16 elems per layer of packed weights

    const int ND = L_TOK * DMODEL;
    const int BIG = 1 << 20;

    auto GD128 = [&](const u16* Aa, const u16* Bha, const u16* Bla, const float* ba_,
                     u16* Ca, const u16* Ab, const u16* Bhb, const u16* Blb,
                     const float* bb_, u16* Cb, int gx, int gy, int K, int ldC,
                     int relu, int ysplit) {
        hipLaunchKernelGGL((gemm_dual<128>), dim3(gx, gy), dim3(256), 0, stream,
                           Aa, Bha, Bla, ba_, Ca, Ab, Bhb, Blb, bb_, Cb, K, ldC, relu, ysplit);
    };
    auto GD64 = [&](const u16* Aa, const u16* Bha, const u16* Bla, const float* ba_,
                    u16* Ca, const u16* Ab, const u16* Bhb, const u16* Blb,
                    const float* bb_, u16* Cb, int gx, int gy, int K, int ldC,
                    int relu, int ysplit) {
        hipLaunchKernelGGL((gemm_dual<64>), dim3(gx, gy), dim3(256), 0, stream,
                           Aa, Bha, Bla, ba_, Ca, Ab, Bhb, Blb, bb_, Cb, K, ldC, relu, ysplit);
    };

    // ---- prepack ALL weights (both layers) in ONE dispatch ----
    hipLaunchKernelGGL(prepack_all, dim3((2 * 720896 + 255) / 256), dim3(256), 0, stream,
                       Wattn, Wbox, battn, bbox, Wv, Wo, W1, W2, wbuf);

    // x = src^T  (tiled, coalesced both sides)
    hipLaunchKernelGGL(xpose_tiled, dim3(4, 256), dim3(256), 0, stream, srcp, x);

    for (int i = 0; i < 2; i++) {
        u16* wb = wbuf + (size_t)i * LSTR;

        hipLaunchKernelGGL(addq_tiled, dim3(4, 256), dim3(256), 0, stream, x, posp, q);

        // merged: comb(q->awb) + Wv(x->val) in one dispatch (grid 4 x 256, ysplit 128)
        GD128(q, wb + 0,      wb + 65536,  (const float*)(wb + 131072), awb,
              x, wb + 163840, wb + 229376, bv + (size_t)i * 256,       val,
              4, 256, 256, 256, 0, 128);

        // sample with FUSED softmax (awb holds raw scores)
        hipLaunchKernelGGL(sample_kernel, dim3(L_TOK * NHEAD * 4 / 256), dim3(256), 0, stream,
                           val, awb, attn);

        // Wo (single problem via dual kernel)
        GD128(attn, wb + 294912, wb + 360448, bo + (size_t)i * 256, tmp,
              attn, wb + 294912, wb + 360448, bo + (size_t)i * 256, tmp,
              4, 128, 256, 256, 0, BIG);

        hipLaunchKernelGGL(ln_rows_bf16, dim3(L_TOK / 4), dim3(256), 0, stream,
                           x, tmp, ln1g + (size_t)i * 256, ln1b + (size_t)i * 256, x);

        // FFN over two half-passes; each half = 8192 rows split across hiddenA/hiddenB
        for (int c = 0; c < 2; c++) {
            const u16* xa = x + (size_t)c * 8192 * 256;
            u16* ya = ffnout + (size_t)c * 8192 * 256;
            GD128(xa,                      wb + 425984, wb + 688128, b1 + (size_t)i * 1024, hiddenA,
                  xa + (size_t)4096 * 256, wb + 425984, wb + 688128, b1 + (size_t)i * 1024, hiddenB,
                  16, 64, 256, 1024, 1, 32);
            GD64(hiddenA, wb + 950272, wb + 1212416, b2 + (size_t)i * 256, ya,
                 hiddenB, wb + 950272, wb + 1212416, b2 + (size_t)i * 256, ya + (size_t)4096 * 256,
                 4, 128, 1024, 256, 0, 64);
        }

        if (i == 0) {
            hipLaunchKernelGGL(ln_rows_bf16, dim3(L_TOK / 4), dim3(256), 0, stream,
                               x, ffnout, ln2g, ln2b, x);
        } else {
            // FINAL: float32 output
            hipLaunchKernelGGL(ln_rows_f32, dim3(L_TOK / 4), dim3(256), 0, stream,
                               x, ffnout, ln2g + 256, ln2b + 256, outp);
        }
    }
}

// Round 11
// 421.462 us; speedup vs baseline: 1.0442x; 1.0442x over previous
//
#include <hip/hip_runtime.h>
#include <cstdint>
#include <cstddef>

typedef unsigned short u16;
typedef unsigned int u32;

#define L_TOK 16384
#define DMODEL 256
#define NHEAD 8
#define HDIM 32

typedef __attribute__((ext_vector_type(8))) short bf16x8;
typedef __attribute__((ext_vector_type(4))) float f32x4;
typedef __attribute__((ext_vector_type(4))) unsigned short u16x4;

__device__ __forceinline__ float bf2f(u16 u) {
    union { unsigned int i; float f; } v; v.i = ((unsigned int)u) << 16; return v.f;
}
__device__ __forceinline__ u16 f2bf(float f) {
    union { unsigned int i; float f; } v; v.f = f;
    unsigned int i = v.i;
    unsigned int r = (i + 0x7FFFu + ((i >> 16) & 1u)) >> 16;
    return (u16)r;
}

// direct global->LDS DMA, 16B per lane; LDS dest is wave-uniform base + lane*16
__device__ __forceinline__ void gload16(const u16* g, u16* l) {
    __builtin_amdgcn_global_load_lds((const __attribute__((address_space(1))) u32*)g,
                                     (__attribute__((address_space(3))) u32*)l, 16, 0, 0);
}

// ---------------- sentinel fill (FLOAT output) ----------------
__global__ __launch_bounds__(256) void fill_kernel(float* __restrict__ out, int n, float v) {
    int t = blockIdx.x * 256 + threadIdx.x;
    if (t < n) out[t] = v;
}

// ---------------- tiled transpose: out[l][d](bf16) = in[d][l](f32), coalesced both sides
__global__ __launch_bounds__(256) void xpose_tiled(const float* __restrict__ in,
                                                   u16* __restrict__ out) {
    __shared__ float t[64][65];
    int d0 = blockIdx.x * 64, l0 = blockIdx.y * 64;
    int c = threadIdx.x & 63, r4 = threadIdx.x >> 6;
#pragma unroll
    for (int it = 0; it < 16; ++it) {
        int r = it * 4 + r4;
        t[r][c] = in[(size_t)(d0 + r) * L_TOK + l0 + c];
    }
    __syncthreads();
#pragma unroll
    for (int it = 0; it < 16; ++it) {
        int r = it * 4 + r4;
        out[(size_t)(l0 + r) * DMODEL + d0 + c] = f2bf(t[c][r]);
    }
}

// ---------------- q[l][d] = x[l][d] + pos[d][l], tiled (pos stays f32) ----------------
__global__ __launch_bounds__(256) void addq_tiled(const u16* __restrict__ x,
                                                  const float* __restrict__ p,
                                                  u16* __restrict__ q) {
    __shared__ float t[64][65];
    int d0 = blockIdx.x * 64, l0 = blockIdx.y * 64;
    int c = threadIdx.x & 63, r4 = threadIdx.x >> 6;
#pragma unroll
    for (int it = 0; it < 16; ++it) {
        int r = it * 4 + r4;
        t[r][c] = p[(size_t)(d0 + r) * L_TOK + l0 + c];
    }
    __syncthreads();
#pragma unroll
    for (int it = 0; it < 16; ++it) {
        int r = it * 4 + r4;
        size_t idx = (size_t)(l0 + r) * DMODEL + d0 + c;
        q[idx] = f2bf(bf2f(x[idx]) + t[c][r]);
    }
}

// ---------------- ONE prepack kernel for all weights, both layers ----------------
// per-layer u16 offsets in wbuf (layer stride 1474560):
//   comb_hi 0 / comb_lo 65536 / comb_bias(f32) 131072   (attn cols 0..199, box 200..231)
//   v 163840/229376   o 294912/360448   w1 425984/688128   w2 950272/1212416
__global__ __launch_bounds__(256) void prepack_all(const float* __restrict__ Wattn,
                                                   const float* __restrict__ Wbox,
                                                   const float* __restrict__ battn,
                                                   const float* __restrict__ bbox,
                                                   const float* __restrict__ Wv,
                                                   const float* __restrict__ Wo,
                                                   const float* __restrict__ W1,
                                                   const float* __restrict__ W2,
                                                   u16* __restrict__ wbuf) {
    const int PER_LAYER = 720896;   // 3*65536 + 2*262144
    int idx = blockIdx.x * 256 + threadIdx.x;
    if (idx >= 2 * PER_LAYER) return;
    int layer = idx / PER_LAYER;
    int r = idx - layer * PER_LAYER;
    u16* wb = wbuf + (size_t)layer * 1474560;
    float w; u16* hi; u16* lo; int pos;
    if (r < 65536) {                       // combined attn+box [256n][256k]
        int n = r >> 8, k = r & 255;
        const float* Wa = Wattn + (size_t)layer * 51200;
        const float* Wb = Wbox  + (size_t)layer * 8192;
        w = (n < 200) ? Wa[(size_t)k * 200 + n]
                      : (n < 232 ? Wb[(size_t)k * 32 + (n - 200)] : 0.f);
        hi = wb; lo = wb + 65536; pos = r;
        if (k == 0) {
            float* bias = (float*)(wb + 131072);
            bias[n] = (n < 200) ? battn[layer * 200 + n]
                                : (n < 232 ? bbox[layer * 32 + n - 200] : 0.f);
        }
    } else if (r < 131072) {               // Wv [256n][256k]
        int rr = r - 65536; int n = rr >> 8, k = rr & 255;
        w = Wv[(size_t)layer * 65536 + (size_t)k * 256 + n];
        hi = wb + 163840; lo = wb + 229376; pos = rr;
    } else if (r < 196608) {               // Wo [256n][256k]
        int rr = r - 131072; int n = rr >> 8, k = rr & 255;
        w = Wo[(size_t)layer * 65536 + (size_t)k * 256 + n];
        hi = wb + 294912; lo = wb + 360448; pos = rr;
    } else if (r < 458752) {               // W1 [1024n][256k]
        int rr = r - 196608; int n = rr >> 8, k = rr & 255;
        w = W1[(size_t)layer * 262144 + (size_t)k * 1024 + n];
        hi = wb + 425984; lo = wb + 688128; pos = rr;
    } else {                               // W2 [256n][1024k]
        int rr = r - 458752; int n = rr >> 10, k = rr & 1023;
        w = W2[(size_t)layer * 262144 + (size_t)k * 256 + n];
        hi = wb + 950272; lo = wb + 1212416; pos = rr;
    }
    u16 h = f2bf(w);
    hi[pos] = h;
    lo[pos] = f2bf(w - bf2f(h));
}

// ---------------- MFMA GEMM (dual): 2-phase dbuf + XOR swizzle + XCD swizzle ----
#define BN 64
#define BK 64

template<int BMv>
__global__ __launch_bounds__(256) void gemm_dual(const u16* __restrict__ Aa,
                                                 const u16* __restrict__ Bha,
                                                 const u16* __restrict__ Bla,
                                                 const float* __restrict__ biasa,
                                                 u16* __restrict__ Ca,
                                                 const u16* __restrict__ Ab,
                                                 const u16* __restrict__ Bhb,
                                                 const u16* __restrict__ Blb,
                                                 const float* __restrict__ biasb,
                                                 u16* __restrict__ Cb,
                                                 int K, int ldC, int relu, int ysplit) {
    constexpr int ASZ = BMv * BK;
    constexpr int BSZ = BN * BK;
    constexpr int ACH = BMv / 32;
    constexpr int NI  = BMv / 32;
    __shared__ __align__(16) u16 lds[2][ASZ + 2 * BSZ];  // BMv=128: 64 KB

    const int tid  = threadIdx.x;
    const int lane = tid & 63;
    const int wave = tid >> 6;
    const int wm = wave >> 1, wn = wave & 1;
    const int row = lane & 15, kch = lane >> 4;

    // XCD-chunked bijective swizzle (T1)
    const int nx = gridDim.x;
    const int nwg = nx * gridDim.y;
    int id = blockIdx.y * nx + blockIdx.x;
    if ((nwg & 7) == 0) { int qq = nwg >> 3; id = (id & 7) * qq + (id >> 3); }
    int by = id / nx;
    const int n0 = (id % nx) * BN;

    // sub-problem select (block-uniform)
    const int sel = by >= ysplit;
    if (sel) by -= ysplit;
    const int m0 = by * BMv;
    const u16*  A    = sel ? Ab    : Aa;
    const u16*  Bhi  = sel ? Bhb   : Bha;
    const u16*  Blo  = sel ? Blb   : Bla;
    const float* bias = sel ? biasb : biasa;
    u16*        C    = sel ? Cb    : Ca;

    // pre-swizzled global source (rule #21): LDS row r, slot s holds global (r, s^(r&7))
    const int srow  = tid >> 3;
    const int sslot = (tid & 7) ^ (srow & 7);
    const u16* ga  = A   + (size_t)(m0 + srow) * K + sslot * 8;
    const u16* gbh = Bhi + (size_t)(n0 + srow) * K + sslot * 8;
    const u16* gbl = Blo + (size_t)(n0 + srow) * K + sslot * 8;

    f32x4 acc[NI][2] = {};
    const int nkt = K / BK;

    auto stage = [&](int kt, int buf) {
        u16* lb = &lds[buf][0];
        const int ko = kt * BK;
#pragma unroll
        for (int it = 0; it < ACH; ++it)
            gload16(ga + ko + (size_t)it * 32 * K, lb + tid * 8 + it * 2048);
#pragma unroll
        for (int it = 0; it < 2; ++it) {
            gload16(gbh + ko + (size_t)it * 32 * K, lb + ASZ + tid * 8 + it * 2048);
            gload16(gbl + ko + (size_t)it * 32 * K, lb + ASZ + BSZ + tid * 8 + it * 2048);
        }
    };

    stage(0, 0);
    __syncthreads();                      // tile 0 ready
    for (int t = 0; t < nkt; ++t) {
        const int cur = t & 1;
        if (t + 1 < nkt) stage(t + 1, cur ^ 1);   // prefetch next tile (other buffer)

        const u16* lb = &lds[cur][0];
#pragma unroll
        for (int kk = 0; kk < 2; ++kk) {
            const int ks = kk * 4 + kch;          // global 16B k-slot 0..7
            bf16x8 af[NI];
#pragma unroll
            for (int i = 0; i < NI; ++i) {
                const int r = wm * (BMv / 2) + i * 16 + row;
                af[i] = *(const bf16x8*)(lb + r * BK + ((ks ^ (r & 7)) * 8));
            }
#pragma unroll
            for (int j = 0; j < 2; ++j) {
                const int rb = wn * 32 + j * 16 + row;
                bf16x8 bh = *(const bf16x8*)(lb + ASZ + rb * BK + ((ks ^ (rb & 7)) * 8));
                bf16x8 bl = *(const bf16x8*)(lb + ASZ + BSZ + rb * BK + ((ks ^ (rb & 7)) * 8));
#pragma unroll
                for (int i = 0; i < NI; ++i) {
                    acc[i][j] = __builtin_amdgcn_mfma_f32_16x16x32_bf16(af[i], bh, acc[i][j], 0, 0, 0);
                    acc[i][j] = __builtin_amdgcn_mfma_f32_16x16x32_bf16(af[i], bl, acc[i][j], 0, 0, 0);
                }
            }
        }
        __syncthreads();   // drains prefetch + joins reads; next buffer ready
    }

    // epilogue: C/D layout col = lane&15, row = (lane>>4)*4 + reg
    const int cm0 = m0 + wm * (BMv / 2) + (lane >> 4) * 4;
    const int cn0 = n0 + wn * 32 + (lane & 15);
#pragma unroll
    for (int j = 0; j < 2; ++j) {
        int cn = cn0 + j * 16;
        float bv_ = bias[cn];
#pragma unroll
        for (int i = 0; i < NI; ++i) {
#pragma unroll
            for (int r = 0; r < 4; ++r) {
                float v = acc[i][j][r] + bv_;
                if (relu) v = fmaxf(v, 0.f);
                C[(size_t)(cm0 + i * 16 + r) * ldC + cn] = f2bf(v);
            }
        }
    }
}

// softmax over combined row layout: aw at row[n*25 .. n*25+24], row = awb + l*256
__global__ __launch_bounds__(256) void softmax_kernel(u16* __restrict__ awb, int total) {
    int t = blockIdx.x * blockDim.x + threadIdx.x;
    if (t >= total) return;
    int l = t >> 3, n = t & 7;
    u16* pp = awb + (size_t)l * 256 + n * 25;
    float v[25];
    float mx = -1e30f;
    for (int k = 0; k < 25; k++) { v[k] = bf2f(pp[k]); mx = fmaxf(mx, v[k]); }
    float s = 0.f;
    for (int k = 0; k < 25; k++) { v[k] = __expf(v[k] - mx); s += v[k]; }
    float inv = 1.f / s;
    for (int k = 0; k < 25; k++) pp[k] = f2bf(v[k] * inv);
}

// one thread = (pair, 16-wide hd half). R6 loop structure EXACTLY (plain k-loop,
// unrolled dy/dx, branchless taps) — only the element width changed (8->16), which
// halves the per-thread share of the box/valid/clamp math. acc arrays static-indexed.
__global__ __launch_bounds__(256) void sample_kernel(const u16* __restrict__ val,
                                                     const u16* __restrict__ awb,
                                                     u16* __restrict__ out) {
    int tid = blockIdx.x * 256 + threadIdx.x;
    int ch = tid & 1;             // hd half (16 elems)
    int pair = tid >> 1;          // l*NH + n
    int n = pair & 7;
    int l = pair >> 3;
    int iy = l >> 7, ix = l & 127;
    float cx = (ix + 0.5f) * (1.f / 128.f);
    float cy = (iy + 0.5f) * (1.f / 128.f);
    const u16* rowp = awb + (size_t)l * 256;
    const u16* o = rowp + 200 + n * 4;
    float bx = cx + bf2f(o[0]) * (0.025f / 8.f);
    float by = cy + bf2f(o[1]) * (0.025f / 8.f);
    float bw = 0.025f + bf2f(o[2]) * (0.025f / 8.f);
    float bh = 0.025f + bf2f(o[3]) * (0.025f / 8.f);
    const u16* awp = rowp + n * 25;
    const u16* vbase = val + n * 32 + ch * 16;
    float acc0[8] = {}, acc1[8] = {};
    for (int k = 0; k < 25; k++) {
        float gx = (float)(k % 5 - 2) * 0.25f;
        float gy = (float)(k / 5 - 2) * 0.25f;
        float xx = (bx + bw * gx) * 128.f - 0.5f;
        float yy = (by + bh * gy) * 128.f - 0.5f;
        float x0 = floorf(xx), y0 = floorf(yy);
        float a_ = bf2f(awp[k]);
#pragma unroll
        for (int dy = 0; dy < 2; dy++) {
#pragma unroll
            for (int dx = 0; dx < 2; dx++) {
                float xi = x0 + dx, yi = y0 + dy;
                float w_ = (1.f - fabsf(xx - xi)) * (1.f - fabsf(yy - yi)) * a_;
                bool valid = (xi >= 0.f) & (xi < 128.f) & (yi >= 0.f) & (yi < 128.f);
                w_ = valid ? w_ : 0.f;
                int ixi = min(max((int)xi, 0), 127);
                int iyi = min(max((int)yi, 0), 127);
                int idx = iyi * 128 + ixi;
                const u16* p = vbase + (size_t)idx * 256;
                bf16x8 va = *(const bf16x8*)(p);
                bf16x8 vb = *(const bf16x8*)(p + 8);
#pragma unroll
                for (int e = 0; e < 8; e++) {
                    acc0[e] += w_ * bf2f((u16)va[e]);
                    acc1[e] += w_ * bf2f((u16)vb[e]);
                }
            }
        }
    }
    bf16x8 ov0, ov1;
#pragma unroll
    for (int e = 0; e < 8; e++) {
        ov0[e] = (short)f2bf(acc0[e]);
        ov1[e] = (short)f2bf(acc1[e]);
    }
    u16* op = out + (size_t)l * 256 + n * 32 + ch * 16;
    *(bf16x8*)(op) = ov0;
    *(bf16x8*)(op + 8) = ov1;
}

// ---------------- LayerNorm: one row per wave, fully in registers ----------------
__global__ __launch_bounds__(256) void ln_rows_bf16(const u16* __restrict__ xin,
                                                    const u16* __restrict__ delta,
                                                    const float* __restrict__ g,
                                                    const float* __restrict__ b,
                                                    u16* __restrict__ out) {
    int lane = threadIdx.x & 63;
    int row = blockIdx.x * 4 + (threadIdx.x >> 6);
    size_t base = (size_t)row * 256 + lane * 4;
    u16x4 xv = *(const u16x4*)(xin + base);
    u16x4 dv = *(const u16x4*)(delta + base);
    float v[4]; float s = 0.f, q = 0.f;
#pragma unroll
    for (int j = 0; j < 4; j++) {
        v[j] = bf2f(xv[j]) + bf2f(dv[j]);
        s += v[j]; q += v[j] * v[j];
    }
#pragma unroll
    for (int off = 1; off < 64; off <<= 1) {
        s += __shfl_xor(s, off, 64);
        q += __shfl_xor(q, off, 64);
    }
    float m = s * (1.f / 256.f);
    float var = q * (1.f / 256.f) - m * m;
    float r = rsqrtf(var + 1e-5f);
    f32x4 gv = *(const f32x4*)(g + lane * 4);
    f32x4 bv2 = *(const f32x4*)(b + lane * 4);
    u16x4 ov;
#pragma unroll
    for (int j = 0; j < 4; j++)
        ov[j] = f2bf((v[j] - m) * r * gv[j] + bv2[j]);
    *(u16x4*)(out + base) = ov;
}

// final LN writes FLOAT32 — d_out is the reference's output dtype (f32)
__global__ __launch_bounds__(256) void ln_rows_f32(const u16* __restrict__ xin,
                                                   const u16* __restrict__ delta,
                                                   const float* __restrict__ g,
                                                   const float* __restrict__ b,
                                                   float* __restrict__ out) {
    int lane = threadIdx.x & 63;
    int row = blockIdx.x * 4 + (threadIdx.x >> 6);
    size_t base = (size_t)row * 256 + lane * 4;
    u16x4 xv = *(const u16x4*)(xin + base);
    u16x4 dv = *(const u16x4*)(delta + base);
    float v[4]; float s = 0.f, q = 0.f;
#pragma unroll
    for (int j = 0; j < 4; j++) {
        v[j] = bf2f(xv[j]) + bf2f(dv[j]);
        s += v[j]; q += v[j] * v[j];
    }
#pragma unroll
    for (int off = 1; off < 64; off <<= 1) {
        s += __shfl_xor(s, off, 64);
        q += __shfl_xor(q, off, 64);
    }
    float m = s * (1.f / 256.f);
    float var = q * (1.f / 256.f) - m * m;
    float r = rsqrtf(var + 1e-5f);
    f32x4 gv = *(const f32x4*)(g + lane * 4);
    f32x4 bv2 = *(const f32x4*)(b + lane * 4);
    f32x4 ov;
#pragma unroll
    for (int j = 0; j < 4; j++)
        ov[j] = (v[j] - m) * r * gv[j] + bv2[j];
    *(f32x4*)(out + base) = ov;
}

extern "C" void kernel_launch(void* const* d_in, const int* in_sizes, int n_in,
                              void* d_out, int out_size, void* d_ws, size_t ws_size,
                              hipStream_t stream) {
    const size_t MiB = 1048576;
    float* outp = (float*)d_out;
    int fillg = (out_size + 255) / 256;

    // ---- environment sentinels ----
    const int exp_sizes[18] = {4194304, 4194304, 131072, 512, 16384, 64, 102400, 400,
                               131072, 512, 524288, 2048, 524288, 512, 512, 512, 512, 512};
    bool env_ok = (n_in == 18) && (ws_size >= 25 * MiB) && (out_size == 4194304);
    if (env_ok) for (int i = 0; i < 18; i++) env_ok = env_ok && (in_sizes[i] == exp_sizes[i]);
    if (!env_ok) {
        hipLaunchKernelGGL(fill_kernel, dim3(fillg), dim3(256), 0, stream, outp, out_size, 3000.f);
        return;
    }

    const float* srcp  = (const float*)d_in[0];
    const float* posp  = (const float*)d_in[1];
    const float* Wv    = (const float*)d_in[2];
    const float* bv    = (const float*)d_in[3];
    const float* Wbox  = (const float*)d_in[4];
    const float* bbox  = (const float*)d_in[5];
    const float* Wattn = (const float*)d_in[6];
    const float* battn = (const float*)d_in[7];
    const float* Wo    = (const float*)d_in[8];
    const float* bo    = (const float*)d_in[9];
    const float* W1    = (const float*)d_in[10];
    const float* b1    = (const float*)d_in[11];
    const float* W2    = (const float*)d_in[12];
    const float* b2    = (const float*)d_in[13];
    const float* ln1g  = (const float*)d_in[14];
    const float* ln1b  = (const float*)d_in[15];
    const float* ln2g  = (const float*)d_in[16];
    const float* ln2b  = (const float*)d_in[17];

    char* ws = (char*)d_ws;
    // ws:   [0,8) x    [8,16) val / hiddenA    [16,24) awb / tmp / ffnout
    // dout: [0,8) q -> attn -> hiddenB (sequential liveness)   [8,~13.6) wbuf
    u16* x       = (u16*)(ws + 0);
    u16* val     = (u16*)(ws + 8 * MiB);
    u16* hiddenA = (u16*)(ws + 8 * MiB);
    u16* awb     = (u16*)(ws + 16 * MiB);
    u16* tmp     = (u16*)(ws + 16 * MiB);
    u16* ffnout  = (u16*)(ws + 16 * MiB);
    u16* q       = (u16*)d_out;
    u16* attn    = (u16*)d_out;
    u16* hiddenB = (u16*)d_out;
    u16* wbuf    = (u16*)((char*)d_out + 8 * MiB);
    const size_t LSTR = 1474560;  // u16 elems per layer of packed weights

    const int ND = L_TOK * DMODEL;
    const int BIG = 1 << 20;

    auto GD128 = [&](const u16* Aa, const u16* Bha, const u16* Bla, const float* ba_,
                     u16* Ca, const u16* Ab, const u16* Bhb, const u16* Blb,
                     const float* bb_, u16* Cb, int gx, int gy, int K, int ldC,
                     int relu, int ysplit) {
        hipLaunchKernelGGL((gemm_dual<128>), dim3(gx, gy), dim3(256), 0, stream,
                           Aa, Bha, Bla, ba_, Ca, Ab, Bhb, Blb, bb_, Cb, K, ldC, relu, ysplit);
    };
    auto GD64 = [&](const u16* Aa, const u16* Bha, const u16* Bla, const float* ba_,
                    u16* Ca, const u16* Ab, const u16* Bhb, const u16* Blb,
                    const float* bb_, u16* Cb, int gx, int gy, int K, int ldC,
                    int relu, int ysplit) {
        hipLaunchKernelGGL((gemm_dual<64>), dim3(gx, gy), dim3(256), 0, stream,
                           Aa, Bha, Bla, ba_, Ca, Ab, Bhb, Blb, bb_, Cb, K, ldC, relu, ysplit);
    };

    // ---- prepack ALL weights (both layers) in ONE dispatch ----
    hipLaunchKernelGGL(prepack_all, dim3((2 * 720896 + 255) / 256), dim3(256), 0, stream,
                       Wattn, Wbox, battn, bbox, Wv, Wo, W1, W2, wbuf);

    // x = src^T  (tiled, coalesced both sides)
    hipLaunchKernelGGL(xpose_tiled, dim3(4, 256), dim3(256), 0, stream, srcp, x);

    for (int i = 0; i < 2; i++) {
        u16* wb = wbuf + (size_t)i * LSTR;

        hipLaunchKernelGGL(addq_tiled, dim3(4, 256), dim3(256), 0, stream, x, posp, q);

        // merged: comb(q->awb) + Wv(x->val) in one dispatch (grid 4 x 256, ysplit 128)
        GD128(q, wb + 0,      wb + 65536,  (const float*)(wb + 131072), awb,
              x, wb + 163840, wb + 229376, bv + (size_t)i * 256,       val,
              4, 256, 256, 256, 0, 128);

        hipLaunchKernelGGL(softmax_kernel, dim3((L_TOK * NHEAD + 255) / 256), dim3(256), 0,
                           stream, awb, L_TOK * NHEAD);

        // sample: 16-wide threads (2 per pair)
        hipLaunchKernelGGL(sample_kernel, dim3(L_TOK * NHEAD * 2 / 256), dim3(256), 0, stream,
                           val, awb, attn);

        // Wo (single problem via dual kernel)
        GD128(attn, wb + 294912, wb + 360448, bo + (size_t)i * 256, tmp,
              attn, wb + 294912, wb + 360448, bo + (size_t)i * 256, tmp,
              4, 128, 256, 256, 0, BIG);

        hipLaunchKernelGGL(ln_rows_bf16, dim3(L_TOK / 4), dim3(256), 0, stream,
                           x, tmp, ln1g + (size_t)i * 256, ln1b + (size_t)i * 256, x);

        // FFN over two half-passes; each half = 8192 rows split across hiddenA/hiddenB
        for (int c = 0; c < 2; c++) {
            const u16* xa = x + (size_t)c * 8192 * 256;
            u16* ya = ffnout + (size_t)c * 8192 * 256;
            GD128(xa,                      wb + 425984, wb + 688128, b1 + (size_t)i * 1024, hiddenA,
                  xa + (size_t)4096 * 256, wb + 425984, wb + 688128, b1 + (size_t)i * 1024, hiddenB,
                  16, 64, 256, 1024, 1, 32);
            GD64(hiddenA, wb + 950272, wb + 1212416, b2 + (size_t)i * 256, ya,
                 hiddenB, wb + 950272, wb + 1212416, b2 + (size_t)i * 256, ya + (size_t)4096 * 256,
                 4, 128, 1024, 256, 0, 64);
        }

        if (i == 0) {
            hipLaunchKernelGGL(ln_rows_bf16, dim3(L_TOK / 4), dim3(256), 0, stream,
                               x, ffnout, ln2g, ln2b, x);
        } else {
            // FINAL: float32 output
            hipLaunchKernelGGL(ln_rows_f32, dim3(L_TOK / 4), dim3(256), 0, stream,
                               x, ffnout, ln2g + 256, ln2b + 256, outp);
        }
    }
}

// Round 13
// 402.110 us; speedup vs baseline: 1.0945x; 1.0481x over previous
//
#include <hip/hip_runtime.h>
#include <cstdint>
#include <cstddef>

typedef unsigned short u16;
typedef unsigned int u32;

#define L_TOK 16384
#define DMODEL 256
#define NHEAD 8
#define HDIM 32

typedef __attribute__((ext_vector_type(8))) short bf16x8;
typedef __attribute__((ext_vector_type(4))) float f32x4;
typedef __attribute__((ext_vector_type(4))) unsigned short u16x4;

__device__ __forceinline__ float bf2f(u16 u) {
    union { unsigned int i; float f; } v; v.i = ((unsigned int)u) << 16; return v.f;
}
__device__ __forceinline__ u16 f2bf(float f) {
    union { unsigned int i; float f; } v; v.f = f;
    unsigned int i = v.i;
    unsigned int r = (i + 0x7FFFu + ((i >> 16) & 1u)) >> 16;
    return (u16)r;
}

// direct global->LDS DMA, 16B per lane; LDS dest is wave-uniform base + lane*16
__device__ __forceinline__ void gload16(const u16* g, u16* l) {
    __builtin_amdgcn_global_load_lds((const __attribute__((address_space(1))) u32*)g,
                                     (__attribute__((address_space(3))) u32*)l, 16, 0, 0);
}

// ---------------- sentinel fill (FLOAT output) ----------------
__global__ __launch_bounds__(256) void fill_kernel(float* __restrict__ out, int n, float v) {
    int t = blockIdx.x * 256 + threadIdx.x;
    if (t < n) out[t] = v;
}

// ---------------- tiled transpose: out[l][d](bf16) = in[d][l](f32), coalesced both sides
__global__ __launch_bounds__(256) void xpose_tiled(const float* __restrict__ in,
                                                   u16* __restrict__ out) {
    __shared__ float t[64][65];
    int d0 = blockIdx.x * 64, l0 = blockIdx.y * 64;
    int c = threadIdx.x & 63, r4 = threadIdx.x >> 6;
#pragma unroll
    for (int it = 0; it < 16; ++it) {
        int r = it * 4 + r4;
        t[r][c] = in[(size_t)(d0 + r) * L_TOK + l0 + c];
    }
    __syncthreads();
#pragma unroll
    for (int it = 0; it < 16; ++it) {
        int r = it * 4 + r4;
        out[(size_t)(l0 + r) * DMODEL + d0 + c] = f2bf(t[c][r]);
    }
}

// ---------------- q[l][d] = x[l][d] + pos[d][l], tiled (pos stays f32) ----------------
__global__ __launch_bounds__(256) void addq_tiled(const u16* __restrict__ x,
                                                  const float* __restrict__ p,
                                                  u16* __restrict__ q) {
    __shared__ float t[64][65];
    int d0 = blockIdx.x * 64, l0 = blockIdx.y * 64;
    int c = threadIdx.x & 63, r4 = threadIdx.x >> 6;
#pragma unroll
    for (int it = 0; it < 16; ++it) {
        int r = it * 4 + r4;
        t[r][c] = p[(size_t)(d0 + r) * L_TOK + l0 + c];
    }
    __syncthreads();
#pragma unroll
    for (int it = 0; it < 16; ++it) {
        int r = it * 4 + r4;
        size_t idx = (size_t)(l0 + r) * DMODEL + d0 + c;
        q[idx] = f2bf(bf2f(x[idx]) + t[c][r]);
    }
}

// ---------------- ONE prepack kernel for all weights, both layers ----------------
// Single bf16 weight (hi only) — lo dropped; weight-quant error (rel 2^-9) is below
// the bf16 activation rounding (2^-8) that dominates absmax. Offsets unchanged:
//   comb_hi 0 / comb_bias(f32) 131072   v 163840   o 294912   w1 425984   w2 950272
__global__ __launch_bounds__(256) void prepack_all(const float* __restrict__ Wattn,
                                                   const float* __restrict__ Wbox,
                                                   const float* __restrict__ battn,
                                                   const float* __restrict__ bbox,
                                                   const float* __restrict__ Wv,
                                                   const float* __restrict__ Wo,
                                                   const float* __restrict__ W1,
                                                   const float* __restrict__ W2,
                                                   u16* __restrict__ wbuf) {
    const int PER_LAYER = 720896;   // 3*65536 + 2*262144 (index space; hi-only stores)
    int idx = blockIdx.x * 256 + threadIdx.x;
    if (idx >= 2 * PER_LAYER) return;
    int layer = idx / PER_LAYER;
    int r = idx - layer * PER_LAYER;
    u16* wb = wbuf + (size_t)layer * 1474560;
    float w; u16* hi; int pos;
    if (r < 65536) {                       // combined attn+box [256n][256k]
        int n = r >> 8, k = r & 255;
        const float* Wa = Wattn + (size_t)layer * 51200;
        const float* Wb = Wbox  + (size_t)layer * 8192;
        w = (n < 200) ? Wa[(size_t)k * 200 + n]
                      : (n < 232 ? Wb[(size_t)k * 32 + (n - 200)] : 0.f);
        hi = wb; pos = r;
        if (k == 0) {
            float* bias = (float*)(wb + 131072);
            bias[n] = (n < 200) ? battn[layer * 200 + n]
                                : (n < 232 ? bbox[layer * 32 + n - 200] : 0.f);
        }
    } else if (r < 131072) {               // Wv [256n][256k]
        int rr = r - 65536; int n = rr >> 8, k = rr & 255;
        w = Wv[(size_t)layer * 65536 + (size_t)k * 256 + n];
        hi = wb + 163840; pos = rr;
    } else if (r < 196608) {               // Wo [256n][256k]
        int rr = r - 131072; int n = rr >> 8, k = rr & 255;
        w = Wo[(size_t)layer * 65536 + (size_t)k * 256 + n];
        hi = wb + 294912; pos = rr;
    } else if (r < 458752) {               // W1 [1024n][256k]
        int rr = r - 196608; int n = rr >> 8, k = rr & 255;
        w = W1[(size_t)layer * 262144 + (size_t)k * 1024 + n];
        hi = wb + 425984; pos = rr;
    } else {                               // W2 [256n][1024k]
        int rr = r - 458752; int n = rr >> 10, k = rr & 1023;
        w = W2[(size_t)layer * 262144 + (size_t)k * 256 + n];
        hi = wb + 950272; pos = rr;
    }
    hi[pos] = f2bf(w);
}

// ---------------- MFMA GEMM (dual): 2-phase dbuf + XOR swizzle + XCD swizzle ----
// Single-bf16 weights: LDS/buffer 24KB (BM=128) -> 3 blocks/CU; one MFMA per (i,j).
#define BN 64
#define BK 64

template<int BMv>
__global__ __launch_bounds__(256) void gemm_dual(const u16* __restrict__ Aa,
                                                 const u16* __restrict__ Bha,
                                                 const float* __restrict__ biasa,
                                                 u16* __restrict__ Ca,
                                                 const u16* __restrict__ Ab,
                                                 const u16* __restrict__ Bhb,
                                                 const float* __restrict__ biasb,
                                                 u16* __restrict__ Cb,
                                                 int K, int ldC, int relu, int ysplit) {
    constexpr int ASZ = BMv * BK;
    constexpr int BSZ = BN * BK;
    constexpr int ACH = BMv / 32;
    constexpr int NI  = BMv / 32;
    __shared__ __align__(16) u16 lds[2][ASZ + BSZ];  // BMv=128: 48 KB total

    const int tid  = threadIdx.x;
    const int lane = tid & 63;
    const int wave = tid >> 6;
    const int wm = wave >> 1, wn = wave & 1;
    const int row = lane & 15, kch = lane >> 4;

    // XCD-chunked bijective swizzle (T1)
    const int nx = gridDim.x;
    const int nwg = nx * gridDim.y;
    int id = blockIdx.y * nx + blockIdx.x;
    if ((nwg & 7) == 0) { int qq = nwg >> 3; id = (id & 7) * qq + (id >> 3); }
    int by = id / nx;
    const int n0 = (id % nx) * BN;

    // sub-problem select (block-uniform)
    const int sel = by >= ysplit;
    if (sel) by -= ysplit;
    const int m0 = by * BMv;
    const u16*  A    = sel ? Ab    : Aa;
    const u16*  Bhi  = sel ? Bhb   : Bha;
    const float* bias = sel ? biasb : biasa;
    u16*        C    = sel ? Cb    : Ca;

    // pre-swizzled global source (rule #21): LDS row r, slot s holds global (r, s^(r&7))
    const int srow  = tid >> 3;
    const int sslot = (tid & 7) ^ (srow & 7);
    const u16* ga  = A   + (size_t)(m0 + srow) * K + sslot * 8;
    const u16* gbh = Bhi + (size_t)(n0 + srow) * K + sslot * 8;

    f32x4 acc[NI][2] = {};
    const int nkt = K / BK;

    auto stage = [&](int kt, int buf) {
        u16* lb = &lds[buf][0];
        const int ko = kt * BK;
#pragma unroll
        for (int it = 0; it < ACH; ++it)
            gload16(ga + ko + (size_t)it * 32 * K, lb + tid * 8 + it * 2048);
#pragma unroll
        for (int it = 0; it < 2; ++it)
            gload16(gbh + ko + (size_t)it * 32 * K, lb + ASZ + tid * 8 + it * 2048);
    };

    stage(0, 0);
    __syncthreads();                      // tile 0 ready
    for (int t = 0; t < nkt; ++t) {
        const int cur = t & 1;
        if (t + 1 < nkt) stage(t + 1, cur ^ 1);   // prefetch next tile (other buffer)

        const u16* lb = &lds[cur][0];
#pragma unroll
        for (int kk = 0; kk < 2; ++kk) {
            const int ks = kk * 4 + kch;          // global 16B k-slot 0..7
            bf16x8 af[NI];
#pragma unroll
            for (int i = 0; i < NI; ++i) {
                const int r = wm * (BMv / 2) + i * 16 + row;
                af[i] = *(const bf16x8*)(lb + r * BK + ((ks ^ (r & 7)) * 8));
            }
#pragma unroll
            for (int j = 0; j < 2; ++j) {
                const int rb = wn * 32 + j * 16 + row;
                bf16x8 bh = *(const bf16x8*)(lb + ASZ + rb * BK + ((ks ^ (rb & 7)) * 8));
#pragma unroll
                for (int i = 0; i < NI; ++i)
                    acc[i][j] = __builtin_amdgcn_mfma_f32_16x16x32_bf16(af[i], bh, acc[i][j], 0, 0, 0);
            }
        }
        __syncthreads();   // drains prefetch + joins reads; next buffer ready
    }

    // epilogue: C/D layout col = lane&15, row = (lane>>4)*4 + reg
    const int cm0 = m0 + wm * (BMv / 2) + (lane >> 4) * 4;
    const int cn0 = n0 + wn * 32 + (lane & 15);
#pragma unroll
    for (int j = 0; j < 2; ++j) {
        int cn = cn0 + j * 16;
        float bv_ = bias[cn];
#pragma unroll
        for (int i = 0; i < NI; ++i) {
#pragma unroll
            for (int r = 0; r < 4; ++r) {
                float v = acc[i][j][r] + bv_;
                if (relu) v = fmaxf(v, 0.f);
                C[(size_t)(cm0 + i * 16 + r) * ldC + cn] = f2bf(v);
            }
        }
    }
}

// softmax over combined row layout: aw at row[n*25 .. n*25+24], row = awb + l*256
__global__ __launch_bounds__(256) void softmax_kernel(u16* __restrict__ awb, int total) {
    int t = blockIdx.x * blockDim.x + threadIdx.x;
    if (t >= total) return;
    int l = t >> 3, n = t & 7;
    u16* pp = awb + (size_t)l * 256 + n * 25;
    float v[25];
    float mx = -1e30f;
    for (int k = 0; k < 25; k++) { v[k] = bf2f(pp[k]); mx = fmaxf(mx, v[k]); }
    float s = 0.f;
    for (int k = 0; k < 25; k++) { v[k] = __expf(v[k] - mx); s += v[k]; }
    float inv = 1.f / s;
    for (int k = 0; k < 25; k++) pp[k] = f2bf(v[k] * inv);
}

// one thread = (pair, 16-wide hd half); R6 loop structure (plain k-loop, unrolled
// dy/dx, branchless taps). Measured 48.6 us — L2-gather-bound plateau.
__global__ __launch_bounds__(256) void sample_kernel(const u16* __restrict__ val,
                                                     const u16* __restrict__ awb,
                                                     u16* __restrict__ out) {
    int tid = blockIdx.x * 256 + threadIdx.x;
    int ch = tid & 1;             // hd half (16 elems)
    int pair = tid >> 1;          // l*NH + n
    int n = pair & 7;
    int l = pair >> 3;
    int iy = l >> 7, ix = l & 127;
    float cx = (ix + 0.5f) * (1.f / 128.f);
    float cy = (iy + 0.5f) * (1.f / 128.f);
    const u16* rowp = awb + (size_t)l * 256;
    const u16* o = rowp + 200 + n * 4;
    float bx = cx + bf2f(o[0]) * (0.025f / 8.f);
    float by = cy + bf2f(o[1]) * (0.025f / 8.f);
    float bw = 0.025f + bf2f(o[2]) * (0.025f / 8.f);
    float bh = 0.025f + bf2f(o[3]) * (0.025f / 8.f);
    const u16* awp = rowp + n * 25;
    const u16* vbase = val + n * 32 + ch * 16;
    float acc0[8] = {}, acc1[8] = {};
    for (int k = 0; k < 25; k++) {
        float gx = (float)(k % 5 - 2) * 0.25f;
        float gy = (float)(k / 5 - 2) * 0.25f;
        float xx = (bx + bw * gx) * 128.f - 0.5f;
        float yy = (by + bh * gy) * 128.f - 0.5f;
        float x0 = floorf(xx), y0 = floorf(yy);
        float a_ = bf2f(awp[k]);
#pragma unroll
        for (int dy = 0; dy < 2; dy++) {
#pragma unroll
            for (int dx = 0; dx < 2; dx++) {
                float xi = x0 + dx, yi = y0 + dy;
                float w_ = (1.f - fabsf(xx - xi)) * (1.f - fabsf(yy - yi)) * a_;
                bool valid = (xi >= 0.f) & (xi < 128.f) & (yi >= 0.f) & (yi < 128.f);
                w_ = valid ? w_ : 0.f;
                int ixi = min(max((int)xi, 0), 127);
                int iyi = min(max((int)yi, 0), 127);
                int idx = iyi * 128 + ixi;
                const u16* p = vbase + (size_t)idx * 256;
                bf16x8 va = *(const bf16x8*)(p);
                bf16x8 vb = *(const bf16x8*)(p + 8);
#pragma unroll
                for (int e = 0; e < 8; e++) {
                    acc0[e] += w_ * bf2f((u16)va[e]);
                    acc1[e] += w_ * bf2f((u16)vb[e]);
                }
            }
        }
    }
    bf16x8 ov0, ov1;
#pragma unroll
    for (int e = 0; e < 8; e++) {
        ov0[e] = (short)f2bf(acc0[e]);
        ov1[e] = (short)f2bf(acc1[e]);
    }
    u16* op = out + (size_t)l * 256 + n * 32 + ch * 16;
    *(bf16x8*)(op) = ov0;
    *(bf16x8*)(op + 8) = ov1;
}

// ---------------- LayerNorm: one row per wave, fully in registers ----------------
__global__ __launch_bounds__(256) void ln_rows_bf16(const u16* __restrict__ xin,
                                                    const u16* __restrict__ delta,
                                                    const float* __restrict__ g,
                                                    const float* __restrict__ b,
                                                    u16* __restrict__ out) {
    int lane = threadIdx.x & 63;
    int row = blockIdx.x * 4 + (threadIdx.x >> 6);
    size_t base = (size_t)row * 256 + lane * 4;
    u16x4 xv = *(const u16x4*)(xin + base);
    u16x4 dv = *(const u16x4*)(delta + base);
    float v[4]; float s = 0.f, q = 0.f;
#pragma unroll
    for (int j = 0; j < 4; j++) {
        v[j] = bf2f(xv[j]) + bf2f(dv[j]);
        s += v[j]; q += v[j] * v[j];
    }
#pragma unroll
    for (int off = 1; off < 64; off <<= 1) {
        s += __shfl_xor(s, off, 64);
        q += __shfl_xor(q, off, 64);
    }
    float m = s * (1.f / 256.f);
    float var = q * (1.f / 256.f) - m * m;
    float r = rsqrtf(var + 1e-5f);
    f32x4 gv = *(const f32x4*)(g + lane * 4);
    f32x4 bv2 = *(const f32x4*)(b + lane * 4);
    u16x4 ov;
#pragma unroll
    for (int j = 0; j < 4; j++)
        ov[j] = f2bf((v[j] - m) * r * gv[j] + bv2[j]);
    *(u16x4*)(out + base) = ov;
}

// final LN writes FLOAT32 — d_out is the reference's output dtype (f32)
__global__ __launch_bounds__(256) void ln_rows_f32(const u16* __restrict__ xin,
                                                   const u16* __restrict__ delta,
                                                   const float* __restrict__ g,
                                                   const float* __restrict__ b,
                                                   float* __restrict__ out) {
    int lane = threadIdx.x & 63;
    int row = blockIdx.x * 4 + (threadIdx.x >> 6);
    size_t base = (size_t)row * 256 + lane * 4;
    u16x4 xv = *(const u16x4*)(xin + base);
    u16x4 dv = *(const u16x4*)(delta + base);
    float v[4]; float s = 0.f, q = 0.f;
#pragma unroll
    for (int j = 0; j < 4; j++) {
        v[j] = bf2f(xv[j]) + bf2f(dv[j]);
        s += v[j]; q += v[j] * v[j];
    }
#pragma unroll
    for (int off = 1; off < 64; off <<= 1) {
        s += __shfl_xor(s, off, 64);
        q += __shfl_xor(q, off, 64);
    }
    float m = s * (1.f / 256.f);
    float var = q * (1.f / 256.f) - m * m;
    float r = rsqrtf(var + 1e-5f);
    f32x4 gv = *(const f32x4*)(g + lane * 4);
    f32x4 bv2 = *(const f32x4*)(b + lane * 4);
    f32x4 ov;
#pragma unroll
    for (int j = 0; j < 4; j++)
        ov[j] = (v[j] - m) * r * gv[j] + bv2[j];
    *(f32x4*)(out + base) = ov;
}

extern "C" void kernel_launch(void* const* d_in, const int* in_sizes, int n_in,
                              void* d_out, int out_size, void* d_ws, size_t ws_size,
                              hipStream_t stream) {
    const size_t MiB = 1048576;
    float* outp = (float*)d_out;
    int fillg = (out_size + 255) / 256;

    // ---- environment sentinels ----
    const int exp_sizes[18] = {4194304, 4194304, 131072, 512, 16384, 64, 102400, 400,
                               131072, 512, 524288, 2048, 524288, 512, 512, 512, 512, 512};
    bool env_ok = (n_in == 18) && (ws_size >= 25 * MiB) && (out_size == 4194304);
    if (env_ok) for (int i = 0; i < 18; i++) env_ok = env_ok && (in_sizes[i] == exp_sizes[i]);
    if (!env_ok) {
        hipLaunchKernelGGL(fill_kernel, dim3(fillg), dim3(256), 0, stream, outp, out_size, 3000.f);
        return;
    }

    const float* srcp  = (const float*)d_in[0];
    const float* posp  = (const float*)d_in[1];
    const float* Wv    = (const float*)d_in[2];
    const float* bv    = (const float*)d_in[3];
    const float* Wbox  = (const float*)d_in[4];
    const float* bbox  = (const float*)d_in[5];
    const float* Wattn = (const float*)d_in[6];
    const float* battn = (const float*)d_in[7];
    const float* Wo    = (const float*)d_in[8];
    const float* bo    = (const float*)d_in[9];
    const float* W1    = (const float*)d_in[10];
    const float* b1    = (const float*)d_in[11];
    const float* W2    = (const float*)d_in[12];
    const float* b2    = (const float*)d_in[13];
    const float* ln1g  = (const float*)d_in[14];
    const float* ln1b  = (const float*)d_in[15];
    const float* ln2g  = (const float*)d_in[16];
    const float* ln2b  = (const float*)d_in[17];

    char* ws = (char*)d_ws;
    // ws:   [0,8) x    [8,16) val / hiddenA    [16,24) awb / tmp / ffnout
    // dout: [0,8) q -> attn -> hiddenB (sequential liveness)   [8,~13.6) wbuf
    u16* x       = (u16*)(ws + 0);
    u16* val     = (u16*)(ws + 8 * MiB);
    u16* hiddenA = (u16*)(ws + 8 * MiB);
    u16* awb     = (u16*)(ws + 16 * MiB);
    u16* tmp     = (u16*)(ws + 16 * MiB);
    u16* ffnout  = (u16*)(ws + 16 * MiB);
    u16* q       = (u16*)d_out;
    u16* attn    = (u16*)d_out;
    u16* hiddenB = (u16*)d_out;
    u16* wbuf    = (u16*)((char*)d_out + 8 * MiB);
    const size_t LSTR = 1474560;  // u16 elems per layer of packed weights

    const int ND = L_TOK * DMODEL;
    const int BIG = 1 << 20;

    auto GD128 = [&](const u16* Aa, const u16* Bha, const float* ba_, u16* Ca,
                     const u16* Ab, const u16* Bhb, const float* bb_, u16* Cb,
                     int gx, int gy, int K, int ldC, int relu, int ysplit) {
        hipLaunchKernelGGL((gemm_dual<128>), dim3(gx, gy), dim3(256), 0, stream,
                           Aa, Bha, ba_, Ca, Ab, Bhb, bb_, Cb, K, ldC, relu, ysplit);
    };
    auto GD64 = [&](const u16* Aa, const u16* Bha, const float* ba_, u16* Ca,
                    const u16* Ab, const u16* Bhb, const float* bb_, u16* Cb,
                    int gx, int gy, int K, int ldC, int relu, int ysplit) {
        hipLaunchKernelGGL((gemm_dual<64>), dim3(gx, gy), dim3(256), 0, stream,
                           Aa, Bha, ba_, Ca, Ab, Bhb, bb_, Cb, K, ldC, relu, ysplit);
    };

    // ---- prepack ALL weights (both layers) in ONE dispatch (hi-only) ----
    hipLaunchKernelGGL(prepack_all, dim3((2 * 720896 + 255) / 256), dim3(256), 0, stream,
                       Wattn, Wbox, battn, bbox, Wv, Wo, W1, W2, wbuf);

    // x = src^T  (tiled, coalesced both sides)
    hipLaunchKernelGGL(xpose_tiled, dim3(4, 256), dim3(256), 0, stream, srcp, x);

    for (int i = 0; i < 2; i++) {
        u16* wb = wbuf + (size_t)i * LSTR;

        hipLaunchKernelGGL(addq_tiled, dim3(4, 256), dim3(256), 0, stream, x, posp, q);

        // merged: comb(q->awb) + Wv(x->val) in one dispatch (grid 4 x 256, ysplit 128)
        GD128(q, wb + 0,      (const float*)(wb + 131072), awb,
              x, wb + 163840, bv + (size_t)i * 256,        val,
              4, 256, 256, 256, 0, 128);

        hipLaunchKernelGGL(softmax_kernel, dim3((L_TOK * NHEAD + 255) / 256), dim3(256), 0,
                           stream, awb, L_TOK * NHEAD);

        // sample: 16-wide threads (2 per pair)
        hipLaunchKernelGGL(sample_kernel, dim3(L_TOK * NHEAD * 2 / 256), dim3(256), 0, stream,
                           val, awb, attn);

        // Wo (single problem via dual kernel)
        GD128(attn, wb + 294912, bo + (size_t)i * 256, tmp,
              attn, wb + 294912, bo + (size_t)i * 256, tmp,
              4, 128, 256, 256, 0, BIG);

        hipLaunchKernelGGL(ln_rows_bf16, dim3(L_TOK / 4), dim3(256), 0, stream,
                           x, tmp, ln1g + (size_t)i * 256, ln1b + (size_t)i * 256, x);

        // FFN over two half-passes; each half = 8192 rows split across hiddenA/hiddenB
        for (int c = 0; c < 2; c++) {
            const u16* xa = x + (size_t)c * 8192 * 256;
            u16* ya = ffnout + (size_t)c * 8192 * 256;
            GD128(xa,                      wb + 425984, b1 + (size_t)i * 1024, hiddenA,
                  xa + (size_t)4096 * 256, wb + 425984, b1 + (size_t)i * 1024, hiddenB,
                  16, 64, 256, 1024, 1, 32);
            GD64(hiddenA, wb + 950272, b2 + (size_t)i * 256, ya,
                 hiddenB, wb + 950272, b2 + (size_t)i * 256, ya + (size_t)4096 * 256,
                 4, 128, 1024, 256, 0, 64);
        }

        if (i == 0) {
            hipLaunchKernelGGL(ln_rows_bf16, dim3(L_TOK / 4), dim3(256), 0, stream,
                               x, ffnout, ln2g, ln2b, x);
        } else {
            // FINAL: float32 output
            hipLaunchKernelGGL(ln_rows_f32, dim3(L_TOK / 4), dim3(256), 0, stream,
                               x, ffnout, ln2g + 256, ln2b + 256, outp);
        }
    }
}

// Round 14
// 379.212 us; speedup vs baseline: 1.1606x; 1.0604x over previous
//
#include <hip/hip_runtime.h>
#include <cstdint>
#include <cstddef>

typedef unsigned short u16;
typedef unsigned int u32;

#define L_TOK 16384
#define DMODEL 256
#define NHEAD 8
#define HDIM 32

typedef __attribute__((ext_vector_type(8))) short bf16x8;
typedef __attribute__((ext_vector_type(4))) float f32x4;
typedef __attribute__((ext_vector_type(4))) unsigned short u16x4;

__device__ __forceinline__ float bf2f(u16 u) {
    union { unsigned int i; float f; } v; v.i = ((unsigned int)u) << 16; return v.f;
}
__device__ __forceinline__ u16 f2bf(float f) {
    union { unsigned int i; float f; } v; v.f = f;
    unsigned int i = v.i;
    unsigned int r = (i + 0x7FFFu + ((i >> 16) & 1u)) >> 16;
    return (u16)r;
}

// direct global->LDS DMA, 16B per lane; LDS dest is wave-uniform base + lane*16
__device__ __forceinline__ void gload16(const u16* g, u16* l) {
    __builtin_amdgcn_global_load_lds((const __attribute__((address_space(1))) u32*)g,
                                     (__attribute__((address_space(3))) u32*)l, 16, 0, 0);
}

// ---------------- sentinel fill (FLOAT output) ----------------
__global__ __launch_bounds__(256) void fill_kernel(float* __restrict__ out, int n, float v) {
    int t = blockIdx.x * 256 + threadIdx.x;
    if (t < n) out[t] = v;
}

// ---------------- tiled transpose: out[l][d](bf16) = in[d][l](f32), coalesced both sides
__global__ __launch_bounds__(256) void xpose_tiled(const float* __restrict__ in,
                                                   u16* __restrict__ out) {
    __shared__ float t[64][65];
    int d0 = blockIdx.x * 64, l0 = blockIdx.y * 64;
    int c = threadIdx.x & 63, r4 = threadIdx.x >> 6;
#pragma unroll
    for (int it = 0; it < 16; ++it) {
        int r = it * 4 + r4;
        t[r][c] = in[(size_t)(d0 + r) * L_TOK + l0 + c];
    }
    __syncthreads();
#pragma unroll
    for (int it = 0; it < 16; ++it) {
        int r = it * 4 + r4;
        out[(size_t)(l0 + r) * DMODEL + d0 + c] = f2bf(t[c][r]);
    }
}

// ---------------- q[l][d] = x[l][d] + pos[d][l], tiled (pos stays f32) ----------------
__global__ __launch_bounds__(256) void addq_tiled(const u16* __restrict__ x,
                                                  const float* __restrict__ p,
                                                  u16* __restrict__ q) {
    __shared__ float t[64][65];
    int d0 = blockIdx.x * 64, l0 = blockIdx.y * 64;
    int c = threadIdx.x & 63, r4 = threadIdx.x >> 6;
#pragma unroll
    for (int it = 0; it < 16; ++it) {
        int r = it * 4 + r4;
        t[r][c] = p[(size_t)(d0 + r) * L_TOK + l0 + c];
    }
    __syncthreads();
#pragma unroll
    for (int it = 0; it < 16; ++it) {
        int r = it * 4 + r4;
        size_t idx = (size_t)(l0 + r) * DMODEL + d0 + c;
        q[idx] = f2bf(bf2f(x[idx]) + t[c][r]);
    }
}

// ---------------- ONE prepack kernel for all weights, both layers ----------------
// Single bf16 weight (hi only). Offsets per layer (stride 1474560):
//   comb_hi 0 / comb_bias(f32) 131072   v 163840   o 294912   w1 425984   w2 950272
__global__ __launch_bounds__(256) void prepack_all(const float* __restrict__ Wattn,
                                                   const float* __restrict__ Wbox,
                                                   const float* __restrict__ battn,
                                                   const float* __restrict__ bbox,
                                                   const float* __restrict__ Wv,
                                                   const float* __restrict__ Wo,
                                                   const float* __restrict__ W1,
                                                   const float* __restrict__ W2,
                                                   u16* __restrict__ wbuf) {
    const int PER_LAYER = 720896;   // 3*65536 + 2*262144 (index space; hi-only stores)
    int idx = blockIdx.x * 256 + threadIdx.x;
    if (idx >= 2 * PER_LAYER) return;
    int layer = idx / PER_LAYER;
    int r = idx - layer * PER_LAYER;
    u16* wb = wbuf + (size_t)layer * 1474560;
    float w; u16* hi; int pos;
    if (r < 65536) {                       // combined attn+box [256n][256k]
        int n = r >> 8, k = r & 255;
        const float* Wa = Wattn + (size_t)layer * 51200;
        const float* Wb = Wbox  + (size_t)layer * 8192;
        w = (n < 200) ? Wa[(size_t)k * 200 + n]
                      : (n < 232 ? Wb[(size_t)k * 32 + (n - 200)] : 0.f);
        hi = wb; pos = r;
        if (k == 0) {
            float* bias = (float*)(wb + 131072);
            bias[n] = (n < 200) ? battn[layer * 200 + n]
                                : (n < 232 ? bbox[layer * 32 + n - 200] : 0.f);
        }
    } else if (r < 131072) {               // Wv [256n][256k]
        int rr = r - 65536; int n = rr >> 8, k = rr & 255;
        w = Wv[(size_t)layer * 65536 + (size_t)k * 256 + n];
        hi = wb + 163840; pos = rr;
    } else if (r < 196608) {               // Wo [256n][256k]
        int rr = r - 131072; int n = rr >> 8, k = rr & 255;
        w = Wo[(size_t)layer * 65536 + (size_t)k * 256 + n];
        hi = wb + 294912; pos = rr;
    } else if (r < 458752) {               // W1 [1024n][256k]
        int rr = r - 196608; int n = rr >> 8, k = rr & 255;
        w = W1[(size_t)layer * 262144 + (size_t)k * 1024 + n];
        hi = wb + 425984; pos = rr;
    } else {                               // W2 [256n][1024k]
        int rr = r - 458752; int n = rr >> 10, k = rr & 1023;
        w = W2[(size_t)layer * 262144 + (size_t)k * 256 + n];
        hi = wb + 950272; pos = rr;
    }
    hi[pos] = f2bf(w);
}

// ---------------- MFMA GEMM (dual): 2-phase dbuf + XOR swizzle + XCD swizzle ----
#define BN 64
#define BK 64

template<int BMv>
__global__ __launch_bounds__(256) void gemm_dual(const u16* __restrict__ Aa,
                                                 const u16* __restrict__ Bha,
                                                 const float* __restrict__ biasa,
                                                 u16* __restrict__ Ca,
                                                 const u16* __restrict__ Ab,
                                                 const u16* __restrict__ Bhb,
                                                 const float* __restrict__ biasb,
                                                 u16* __restrict__ Cb,
                                                 int K, int ldC, int relu, int ysplit) {
    constexpr int ASZ = BMv * BK;
    constexpr int BSZ = BN * BK;
    constexpr int ACH = BMv / 32;
    constexpr int NI  = BMv / 32;
    __shared__ __align__(16) u16 lds[2][ASZ + BSZ];  // BMv=128: 48 KB total

    const int tid  = threadIdx.x;
    const int lane = tid & 63;
    const int wave = tid >> 6;
    const int wm = wave >> 1, wn = wave & 1;
    const int row = lane & 15, kch = lane >> 4;

    // XCD-chunked bijective swizzle (T1)
    const int nx = gridDim.x;
    const int nwg = nx * gridDim.y;
    int id = blockIdx.y * nx + blockIdx.x;
    if ((nwg & 7) == 0) { int qq = nwg >> 3; id = (id & 7) * qq + (id >> 3); }
    int by = id / nx;
    const int n0 = (id % nx) * BN;

    // sub-problem select (block-uniform)
    const int sel = by >= ysplit;
    if (sel) by -= ysplit;
    const int m0 = by * BMv;
    const u16*  A    = sel ? Ab    : Aa;
    const u16*  Bhi  = sel ? Bhb   : Bha;
    const float* bias = sel ? biasb : biasa;
    u16*        C    = sel ? Cb    : Ca;

    // pre-swizzled global source (rule #21): LDS row r, slot s holds global (r, s^(r&7))
    const int srow  = tid >> 3;
    const int sslot = (tid & 7) ^ (srow & 7);
    const u16* ga  = A   + (size_t)(m0 + srow) * K + sslot * 8;
    const u16* gbh = Bhi + (size_t)(n0 + srow) * K + sslot * 8;

    f32x4 acc[NI][2] = {};
    const int nkt = K / BK;

    auto stage = [&](int kt, int buf) {
        u16* lb = &lds[buf][0];
        const int ko = kt * BK;
#pragma unroll
        for (int it = 0; it < ACH; ++it)
            gload16(ga + ko + (size_t)it * 32 * K, lb + tid * 8 + it * 2048);
#pragma unroll
        for (int it = 0; it < 2; ++it)
            gload16(gbh + ko + (size_t)it * 32 * K, lb + ASZ + tid * 8 + it * 2048);
    };

    stage(0, 0);
    __syncthreads();                      // tile 0 ready
    for (int t = 0; t < nkt; ++t) {
        const int cur = t & 1;
        if (t + 1 < nkt) stage(t + 1, cur ^ 1);   // prefetch next tile (other buffer)

        const u16* lb = &lds[cur][0];
#pragma unroll
        for (int kk = 0; kk < 2; ++kk) {
            const int ks = kk * 4 + kch;          // global 16B k-slot 0..7
            bf16x8 af[NI];
#pragma unroll
            for (int i = 0; i < NI; ++i) {
                const int r = wm * (BMv / 2) + i * 16 + row;
                af[i] = *(const bf16x8*)(lb + r * BK + ((ks ^ (r & 7)) * 8));
            }
#pragma unroll
            for (int j = 0; j < 2; ++j) {
                const int rb = wn * 32 + j * 16 + row;
                bf16x8 bh = *(const bf16x8*)(lb + ASZ + rb * BK + ((ks ^ (rb & 7)) * 8));
#pragma unroll
                for (int i = 0; i < NI; ++i)
                    acc[i][j] = __builtin_amdgcn_mfma_f32_16x16x32_bf16(af[i], bh, acc[i][j], 0, 0, 0);
            }
        }
        __syncthreads();   // drains prefetch + joins reads; next buffer ready
    }

    // epilogue: C/D layout col = lane&15, row = (lane>>4)*4 + reg
    const int cm0 = m0 + wm * (BMv / 2) + (lane >> 4) * 4;
    const int cn0 = n0 + wn * 32 + (lane & 15);
#pragma unroll
    for (int j = 0; j < 2; ++j) {
        int cn = cn0 + j * 16;
        float bv_ = bias[cn];
#pragma unroll
        for (int i = 0; i < NI; ++i) {
#pragma unroll
            for (int r = 0; r < 4; ++r) {
                float v = acc[i][j][r] + bv_;
                if (relu) v = fmaxf(v, 0.f);
                C[(size_t)(cm0 + i * 16 + r) * ldC + cn] = f2bf(v);
            }
        }
    }
}

// one thread = (pair, 16-wide hd half); FUSED softmax. Main loop is the R13/R6
// structure byte-for-byte (plain k-loop, compiler-chosen unroll — the R10 regression
// was `#pragma unroll 1` serialization, not the fusion). Stats passes are plain
// scalar loops (no v[25] array -> no scratch, rule #20).
__global__ __launch_bounds__(256) void sample_kernel(const u16* __restrict__ val,
                                                     const u16* __restrict__ awb,
                                                     u16* __restrict__ out) {
    int tid = blockIdx.x * 256 + threadIdx.x;
    int ch = tid & 1;             // hd half (16 elems)
    int pair = tid >> 1;          // l*NH + n
    int n = pair & 7;
    int l = pair >> 3;
    int iy = l >> 7, ix = l & 127;
    float cx = (ix + 0.5f) * (1.f / 128.f);
    float cy = (iy + 0.5f) * (1.f / 128.f);
    const u16* rowp = awb + (size_t)l * 256;
    const u16* o = rowp + 200 + n * 4;
    float bx = cx + bf2f(o[0]) * (0.025f / 8.f);
    float by = cy + bf2f(o[1]) * (0.025f / 8.f);
    float bw = 0.025f + bf2f(o[2]) * (0.025f / 8.f);
    float bh = 0.025f + bf2f(o[3]) * (0.025f / 8.f);
    const u16* awp = rowp + n * 25;   // RAW scores — softmax applied inline below
    const u16* vbase = val + n * 32 + ch * 16;

    // softmax stats (f32, no bf16 round-trip on the weights)
    float mx = -1e30f;
    for (int k = 0; k < 25; k++) mx = fmaxf(mx, bf2f(awp[k]));
    float s = 0.f;
    for (int k = 0; k < 25; k++) s += __expf(bf2f(awp[k]) - mx);
    float inv = 1.f / s;

    float acc0[8] = {}, acc1[8] = {};
    for (int k = 0; k < 25; k++) {
        float gx = (float)(k % 5 - 2) * 0.25f;
        float gy = (float)(k / 5 - 2) * 0.25f;
        float xx = (bx + bw * gx) * 128.f - 0.5f;
        float yy = (by + bh * gy) * 128.f - 0.5f;
        float x0 = floorf(xx), y0 = floorf(yy);
        float a_ = __expf(bf2f(awp[k]) - mx) * inv;
#pragma unroll
        for (int dy = 0; dy < 2; dy++) {
#pragma unroll
            for (int dx = 0; dx < 2; dx++) {
                float xi = x0 + dx, yi = y0 + dy;
                float w_ = (1.f - fabsf(xx - xi)) * (1.f - fabsf(yy - yi)) * a_;
                bool valid = (xi >= 0.f) & (xi < 128.f) & (yi >= 0.f) & (yi < 128.f);
                w_ = valid ? w_ : 0.f;
                int ixi = min(max((int)xi, 0), 127);
                int iyi = min(max((int)yi, 0), 127);
                int idx = iyi * 128 + ixi;
                const u16* p = vbase + (size_t)idx * 256;
                bf16x8 va = *(const bf16x8*)(p);
                bf16x8 vb = *(const bf16x8*)(p + 8);
#pragma unroll
                for (int e = 0; e < 8; e++) {
                    acc0[e] += w_ * bf2f((u16)va[e]);
                    acc1[e] += w_ * bf2f((u16)vb[e]);
                }
            }
        }
    }
    bf16x8 ov0, ov1;
#pragma unroll
    for (int e = 0; e < 8; e++) {
        ov0[e] = (short)f2bf(acc0[e]);
        ov1[e] = (short)f2bf(acc1[e]);
    }
    u16* op = out + (size_t)l * 256 + n * 32 + ch * 16;
    *(bf16x8*)(op) = ov0;
    *(bf16x8*)(op + 8) = ov1;
}

// ---------------- LayerNorm: one row per wave, fully in registers ----------------
__global__ __launch_bounds__(256) void ln_rows_bf16(const u16* __restrict__ xin,
                                                    const u16* __restrict__ delta,
                                                    const float* __restrict__ g,
                                                    const float* __restrict__ b,
                                                    u16* __restrict__ out) {
    int lane = threadIdx.x & 63;
    int row = blockIdx.x * 4 + (threadIdx.x >> 6);
    size_t base = (size_t)row * 256 + lane * 4;
    u16x4 xv = *(const u16x4*)(xin + base);
    u16x4 dv = *(const u16x4*)(delta + base);
    float v[4]; float s = 0.f, q = 0.f;
#pragma unroll
    for (int j = 0; j < 4; j++) {
        v[j] = bf2f(xv[j]) + bf2f(dv[j]);
        s += v[j]; q += v[j] * v[j];
    }
#pragma unroll
    for (int off = 1; off < 64; off <<= 1) {
        s += __shfl_xor(s, off, 64);
        q += __shfl_xor(q, off, 64);
    }
    float m = s * (1.f / 256.f);
    float var = q * (1.f / 256.f) - m * m;
    float r = rsqrtf(var + 1e-5f);
    f32x4 gv = *(const f32x4*)(g + lane * 4);
    f32x4 bv2 = *(const f32x4*)(b + lane * 4);
    u16x4 ov;
#pragma unroll
    for (int j = 0; j < 4; j++)
        ov[j] = f2bf((v[j] - m) * r * gv[j] + bv2[j]);
    *(u16x4*)(out + base) = ov;
}

// final LN writes FLOAT32 — d_out is the reference's output dtype (f32)
__global__ __launch_bounds__(256) void ln_rows_f32(const u16* __restrict__ xin,
                                                   const u16* __restrict__ delta,
                                                   const float* __restrict__ g,
                                                   const float* __restrict__ b,
                                                   float* __restrict__ out) {
    int lane = threadIdx.x & 63;
    int row = blockIdx.x * 4 + (threadIdx.x >> 6);
    size_t base = (size_t)row * 256 + lane * 4;
    u16x4 xv = *(const u16x4*)(xin + base);
    u16x4 dv = *(const u16x4*)(delta + base);
    float v[4]; float s = 0.f, q = 0.f;
#pragma unroll
    for (int j = 0; j < 4; j++) {
        v[j] = bf2f(xv[j]) + bf2f(dv[j]);
        s += v[j]; q += v[j] * v[j];
    }
#pragma unroll
    for (int off = 1; off < 64; off <<= 1) {
        s += __shfl_xor(s, off, 64);
        q += __shfl_xor(q, off, 64);
    }
    float m = s * (1.f / 256.f);
    float var = q * (1.f / 256.f) - m * m;
    float r = rsqrtf(var + 1e-5f);
    f32x4 gv = *(const f32x4*)(g + lane * 4);
    f32x4 bv2 = *(const f32x4*)(b + lane * 4);
    f32x4 ov;
#pragma unroll
    for (int j = 0; j < 4; j++)
        ov[j] = (v[j] - m) * r * gv[j] + bv2[j];
    *(f32x4*)(out + base) = ov;
}

extern "C" void kernel_launch(void* const* d_in, const int* in_sizes, int n_in,
                              void* d_out, int out_size, void* d_ws, size_t ws_size,
                              hipStream_t stream) {
    const size_t MiB = 1048576;
    float* outp = (float*)d_out;
    int fillg = (out_size + 255) / 256;

    // ---- environment sentinels ----
    const int exp_sizes[18] = {4194304, 4194304, 131072, 512, 16384, 64, 102400, 400,
                               131072, 512, 524288, 2048, 524288, 512, 512, 512, 512, 512};
    bool env_ok = (n_in == 18) && (ws_size >= 25 * MiB) && (out_size == 4194304);
    if (env_ok) for (int i = 0; i < 18; i++) env_ok = env_ok && (in_sizes[i] == exp_sizes[i]);
    if (!env_ok) {
        hipLaunchKernelGGL(fill_kernel, dim3(fillg), dim3(256), 0, stream, outp, out_size, 3000.f);
        return;
    }

    const float* srcp  = (const float*)d_in[0];
    const float* posp  = (const float*)d_in[1];
    const float* Wv    = (const float*)d_in[2];
    const float* bv    = (const float*)d_in[3];
    const float* Wbox  = (const float*)d_in[4];
    const float* bbox  = (const float*)d_in[5];
    const float* Wattn = (const float*)d_in[6];
    const float* battn = (const float*)d_in[7];
    const float* Wo    = (const float*)d_in[8];
    const float* bo    = (const float*)d_in[9];
    const float* W1    = (const float*)d_in[10];
    const float* b1    = (const float*)d_in[11];
    const float* W2    = (const float*)d_in[12];
    const float* b2    = (const float*)d_in[13];
    const float* ln1g  = (const float*)d_in[14];
    const float* ln1b  = (const float*)d_in[15];
    const float* ln2g  = (const float*)d_in[16];
    const float* ln2b  = (const float*)d_in[17];

    char* ws = (char*)d_ws;
    // ws:   [0,8) x    [8,16) val / hiddenA    [16,24) awb / tmp / ffnout
    // dout: [0,8) q -> attn -> hiddenB (sequential liveness)   [8,~13.6) wbuf
    u16* x       = (u16*)(ws + 0);
    u16* val     = (u16*)(ws + 8 * MiB);
    u16* hiddenA = (u16*)(ws + 8 * MiB);
    u16* awb     = (u16*)(ws + 16 * MiB);
    u16* tmp     = (u16*)(ws + 16 * MiB);
    u16* ffnout  = (u16*)(ws + 16 * MiB);
    u16* q       = (u16*)d_out;
    u16* attn    = (u16*)d_out;
    u16* hiddenB = (u16*)d_out;
    u16* wbuf    = (u16*)((char*)d_out + 8 * MiB);
    const size_t LSTR = 1474560;  // u16 elems per layer of packed weights

    const int ND = L_TOK * DMODEL;
    const int BIG = 1 << 20;

    auto GD128 = [&](const u16* Aa, const u16* Bha, const float* ba_, u16* Ca,
                     const u16* Ab, const u16* Bhb, const float* bb_, u16* Cb,
                     int gx, int gy, int K, int ldC, int relu, int ysplit) {
        hipLaunchKernelGGL((gemm_dual<128>), dim3(gx, gy), dim3(256), 0, stream,
                           Aa, Bha, ba_, Ca, Ab, Bhb, bb_, Cb, K, ldC, relu, ysplit);
    };
    auto GD64 = [&](const u16* Aa, const u16* Bha, const float* ba_, u16* Ca,
                    const u16* Ab, const u16* Bhb, const float* bb_, u16* Cb,
                    int gx, int gy, int K, int ldC, int relu, int ysplit) {
        hipLaunchKernelGGL((gemm_dual<64>), dim3(gx, gy), dim3(256), 0, stream,
                           Aa, Bha, ba_, Ca, Ab, Bhb, bb_, Cb, K, ldC, relu, ysplit);
    };

    // ---- prepack ALL weights (both layers) in ONE dispatch (hi-only) ----
    hipLaunchKernelGGL(prepack_all, dim3((2 * 720896 + 255) / 256), dim3(256), 0, stream,
                       Wattn, Wbox, battn, bbox, Wv, Wo, W1, W2, wbuf);

    // x = src^T  (tiled, coalesced both sides)
    hipLaunchKernelGGL(xpose_tiled, dim3(4, 256), dim3(256), 0, stream, srcp, x);

    for (int i = 0; i < 2; i++) {
        u16* wb = wbuf + (size_t)i * LSTR;

        hipLaunchKernelGGL(addq_tiled, dim3(4, 256), dim3(256), 0, stream, x, posp, q);

        // merged: comb(q->awb) + Wv(x->val) in one dispatch (grid 4 x 256, ysplit 128)
        GD128(q, wb + 0,      (const float*)(wb + 131072), awb,
              x, wb + 163840, bv + (size_t)i * 256,        val,
              4, 256, 256, 256, 0, 128);

        // sample with FUSED softmax (awb holds raw scores); 16-wide threads
        hipLaunchKernelGGL(sample_kernel, dim3(L_TOK * NHEAD * 2 / 256), dim3(256), 0, stream,
                           val, awb, attn);

        // Wo (single problem via dual kernel)
        GD128(attn, wb + 294912, bo + (size_t)i * 256, tmp,
              attn, wb + 294912, bo + (size_t)i * 256, tmp,
              4, 128, 256, 256, 0, BIG);

        hipLaunchKernelGGL(ln_rows_bf16, dim3(L_TOK / 4), dim3(256), 0, stream,
                           x, tmp, ln1g + (size_t)i * 256, ln1b + (size_t)i * 256, x);

        // FFN over two half-passes; each half = 8192 rows split across hiddenA/hiddenB
        for (int c = 0; c < 2; c++) {
            const u16* xa = x + (size_t)c * 8192 * 256;
            u16* ya = ffnout + (size_t)c * 8192 * 256;
            GD128(xa,                      wb + 425984, b1 + (size_t)i * 1024, hiddenA,
                  xa + (size_t)4096 * 256, wb + 425984, b1 + (size_t)i * 1024, hiddenB,
                  16, 64, 256, 1024, 1, 32);
            GD64(hiddenA, wb + 950272, b2 + (size_t)i * 256, ya,
                 hiddenB, wb + 950272, b2 + (size_t)i * 256, ya + (size_t)4096 * 256,
                 4, 128, 1024, 256, 0, 64);
        }

        if (i == 0) {
            hipLaunchKernelGGL(ln_rows_bf16, dim3(L_TOK / 4), dim3(256), 0, stream,
                               x, ffnout, ln2g, ln2b, x);
        } else {
            // FINAL: float32 output
            hipLaunchKernelGGL(ln_rows_f32, dim3(L_TOK / 4), dim3(256), 0, stream,
                               x, ffnout, ln2g + 256, ln2b + 256, outp);
        }
    }
}

// Round 15
// 366.959 us; speedup vs baseline: 1.1993x; 1.0334x over previous
//
#include <hip/hip_runtime.h>
#include <cstdint>
#include <cstddef>

typedef unsigned short u16;
typedef unsigned int u32;

#define L_TOK 16384
#define DMODEL 256
#define NHEAD 8
#define HDIM 32

typedef __attribute__((ext_vector_type(8))) short bf16x8;
typedef __attribute__((ext_vector_type(4))) float f32x4;
typedef __attribute__((ext_vector_type(4))) unsigned short u16x4;

__device__ __forceinline__ float bf2f(u16 u) {
    union { unsigned int i; float f; } v; v.i = ((unsigned int)u) << 16; return v.f;
}
__device__ __forceinline__ u16 f2bf(float f) {
    union { unsigned int i; float f; } v; v.f = f;
    unsigned int i = v.i;
    unsigned int r = (i + 0x7FFFu + ((i >> 16) & 1u)) >> 16;
    return (u16)r;
}

// direct global->LDS DMA, 16B per lane; LDS dest is wave-uniform base + lane*16
__device__ __forceinline__ void gload16(const u16* g, u16* l) {
    __builtin_amdgcn_global_load_lds((const __attribute__((address_space(1))) u32*)g,
                                     (__attribute__((address_space(3))) u32*)l, 16, 0, 0);
}

// ---------------- sentinel fill (FLOAT output) ----------------
__global__ __launch_bounds__(256) void fill_kernel(float* __restrict__ out, int n, float v) {
    int t = blockIdx.x * 256 + threadIdx.x;
    if (t < n) out[t] = v;
}

// ---------------- tiled transpose: out[l][d](bf16) = in[d][l](f32), coalesced both sides
__global__ __launch_bounds__(256) void xpose_tiled(const float* __restrict__ in,
                                                   u16* __restrict__ out) {
    __shared__ float t[64][65];
    int d0 = blockIdx.x * 64, l0 = blockIdx.y * 64;
    int c = threadIdx.x & 63, r4 = threadIdx.x >> 6;
#pragma unroll
    for (int it = 0; it < 16; ++it) {
        int r = it * 4 + r4;
        t[r][c] = in[(size_t)(d0 + r) * L_TOK + l0 + c];
    }
    __syncthreads();
#pragma unroll
    for (int it = 0; it < 16; ++it) {
        int r = it * 4 + r4;
        out[(size_t)(l0 + r) * DMODEL + d0 + c] = f2bf(t[c][r]);
    }
}

// ---------------- q[l][d] = x[l][d] + pos[d][l], tiled (pos stays f32) ----------------
__global__ __launch_bounds__(256) void addq_tiled(const u16* __restrict__ x,
                                                  const float* __restrict__ p,
                                                  u16* __restrict__ q) {
    __shared__ float t[64][65];
    int d0 = blockIdx.x * 64, l0 = blockIdx.y * 64;
    int c = threadIdx.x & 63, r4 = threadIdx.x >> 6;
#pragma unroll
    for (int it = 0; it < 16; ++it) {
        int r = it * 4 + r4;
        t[r][c] = p[(size_t)(d0 + r) * L_TOK + l0 + c];
    }
    __syncthreads();
#pragma unroll
    for (int it = 0; it < 16; ++it) {
        int r = it * 4 + r4;
        size_t idx = (size_t)(l0 + r) * DMODEL + d0 + c;
        q[idx] = f2bf(bf2f(x[idx]) + t[c][r]);
    }
}

// ---------------- ONE prepack kernel for all weights, both layers ----------------
// Single bf16 weight (hi only). Offsets per layer (stride 1474560):
//   comb_hi 0 / comb_bias(f32) 131072   v 163840   o 294912   w1 425984   w2 950272
__global__ __launch_bounds__(256) void prepack_all(const float* __restrict__ Wattn,
                                                   const float* __restrict__ Wbox,
                                                   const float* __restrict__ battn,
                                                   const float* __restrict__ bbox,
                                                   const float* __restrict__ Wv,
                                                   const float* __restrict__ Wo,
                                                   const float* __restrict__ W1,
                                                   const float* __restrict__ W2,
                                                   u16* __restrict__ wbuf) {
    const int PER_LAYER = 720896;   // 3*65536 + 2*262144 (index space; hi-only stores)
    int idx = blockIdx.x * 256 + threadIdx.x;
    if (idx >= 2 * PER_LAYER) return;
    int layer = idx / PER_LAYER;
    int r = idx - layer * PER_LAYER;
    u16* wb = wbuf + (size_t)layer * 1474560;
    float w; u16* hi; int pos;
    if (r < 65536) {                       // combined attn+box [256n][256k]
        int n = r >> 8, k = r & 255;
        const float* Wa = Wattn + (size_t)layer * 51200;
        const float* Wb = Wbox  + (size_t)layer * 8192;
        w = (n < 200) ? Wa[(size_t)k * 200 + n]
                      : (n < 232 ? Wb[(size_t)k * 32 + (n - 200)] : 0.f);
        hi = wb; pos = r;
        if (k == 0) {
            float* bias = (float*)(wb + 131072);
            bias[n] = (n < 200) ? battn[layer * 200 + n]
                                : (n < 232 ? bbox[layer * 32 + n - 200] : 0.f);
        }
    } else if (r < 131072) {               // Wv [256n][256k]
        int rr = r - 65536; int n = rr >> 8, k = rr & 255;
        w = Wv[(size_t)layer * 65536 + (size_t)k * 256 + n];
        hi = wb + 163840; pos = rr;
    } else if (r < 196608) {               // Wo [256n][256k]
        int rr = r - 131072; int n = rr >> 8, k = rr & 255;
        w = Wo[(size_t)layer * 65536 + (size_t)k * 256 + n];
        hi = wb + 294912; pos = rr;
    } else if (r < 458752) {               // W1 [1024n][256k]
        int rr = r - 196608; int n = rr >> 8, k = rr & 255;
        w = W1[(size_t)layer * 262144 + (size_t)k * 1024 + n];
        hi = wb + 425984; pos = rr;
    } else {                               // W2 [256n][1024k]
        int rr = r - 458752; int n = rr >> 10, k = rr & 1023;
        w = W2[(size_t)layer * 262144 + (size_t)k * 256 + n];
        hi = wb + 950272; pos = rr;
    }
    hi[pos] = f2bf(w);
}

// ---------------- MFMA GEMM (dual): 2-phase dbuf + XOR swizzle + XCD swizzle ----
#define BN 64
#define BK 64

template<int BMv>
__global__ __launch_bounds__(256) void gemm_dual(const u16* __restrict__ Aa,
                                                 const u16* __restrict__ Bha,
                                                 const float* __restrict__ biasa,
                                                 u16* __restrict__ Ca,
                                                 const u16* __restrict__ Ab,
                                                 const u16* __restrict__ Bhb,
                                                 const float* __restrict__ biasb,
                                                 u16* __restrict__ Cb,
                                                 int K, int ldC, int relu, int ysplit) {
    constexpr int ASZ = BMv * BK;
    constexpr int BSZ = BN * BK;
    constexpr int ACH = BMv / 32;
    constexpr int NI  = BMv / 32;
    __shared__ __align__(16) u16 lds[2][ASZ + BSZ];  // BMv=128: 48 KB total

    const int tid  = threadIdx.x;
    const int lane = tid & 63;
    const int wave = tid >> 6;
    const int wm = wave >> 1, wn = wave & 1;
    const int row = lane & 15, kch = lane >> 4;

    // XCD-chunked bijective swizzle (T1)
    const int nx = gridDim.x;
    const int nwg = nx * gridDim.y;
    int id = blockIdx.y * nx + blockIdx.x;
    if ((nwg & 7) == 0) { int qq = nwg >> 3; id = (id & 7) * qq + (id >> 3); }
    int by = id / nx;
    const int n0 = (id % nx) * BN;

    // sub-problem select (block-uniform)
    const int sel = by >= ysplit;
    if (sel) by -= ysplit;
    const int m0 = by * BMv;
    const u16*  A    = sel ? Ab    : Aa;
    const u16*  Bhi  = sel ? Bhb   : Bha;
    const float* bias = sel ? biasb : biasa;
    u16*        C    = sel ? Cb    : Ca;

    // pre-swizzled global source (rule #21): LDS row r, slot s holds global (r, s^(r&7))
    const int srow  = tid >> 3;
    const int sslot = (tid & 7) ^ (srow & 7);
    const u16* ga  = A   + (size_t)(m0 + srow) * K + sslot * 8;
    const u16* gbh = Bhi + (size_t)(n0 + srow) * K + sslot * 8;

    f32x4 acc[NI][2] = {};
    const int nkt = K / BK;

    auto stage = [&](int kt, int buf) {
        u16* lb = &lds[buf][0];
        const int ko = kt * BK;
#pragma unroll
        for (int it = 0; it < ACH; ++it)
            gload16(ga + ko + (size_t)it * 32 * K, lb + tid * 8 + it * 2048);
#pragma unroll
        for (int it = 0; it < 2; ++it)
            gload16(gbh + ko + (size_t)it * 32 * K, lb + ASZ + tid * 8 + it * 2048);
    };

    stage(0, 0);
    __syncthreads();                      // tile 0 ready
    for (int t = 0; t < nkt; ++t) {
        const int cur = t & 1;
        if (t + 1 < nkt) stage(t + 1, cur ^ 1);   // prefetch next tile (other buffer)

        const u16* lb = &lds[cur][0];
#pragma unroll
        for (int kk = 0; kk < 2; ++kk) {
            const int ks = kk * 4 + kch;          // global 16B k-slot 0..7
            bf16x8 af[NI];
#pragma unroll
            for (int i = 0; i < NI; ++i) {
                const int r = wm * (BMv / 2) + i * 16 + row;
                af[i] = *(const bf16x8*)(lb + r * BK + ((ks ^ (r & 7)) * 8));
            }
#pragma unroll
            for (int j = 0; j < 2; ++j) {
                const int rb = wn * 32 + j * 16 + row;
                bf16x8 bh = *(const bf16x8*)(lb + ASZ + rb * BK + ((ks ^ (rb & 7)) * 8));
#pragma unroll
                for (int i = 0; i < NI; ++i)
                    acc[i][j] = __builtin_amdgcn_mfma_f32_16x16x32_bf16(af[i], bh, acc[i][j], 0, 0, 0);
            }
        }
        __syncthreads();   // drains prefetch + joins reads; next buffer ready
    }

    // epilogue: C/D layout col = lane&15, row = (lane>>4)*4 + reg
    const int cm0 = m0 + wm * (BMv / 2) + (lane >> 4) * 4;
    const int cn0 = n0 + wn * 32 + (lane & 15);
#pragma unroll
    for (int j = 0; j < 2; ++j) {
        int cn = cn0 + j * 16;
        float bv_ = bias[cn];
#pragma unroll
        for (int i = 0; i < NI; ++i) {
#pragma unroll
            for (int r = 0; r < 4; ++r) {
                float v = acc[i][j][r] + bv_;
                if (relu) v = fmaxf(v, 0.f);
                C[(size_t)(cm0 + i * 16 + r) * ldC + cn] = f2bf(v);
            }
        }
    }
}

// one thread = (pair, 16-wide hd half); FUSED softmax; R13/R6 main-loop structure.
// NEW (R15): XCD-chunked block swizzle — consecutive-l blocks (overlapping val tap
// windows) co-locate on one XCD so the shared val lines stay in that XCD's L2
// (~1.3 MB band per XCD) instead of being re-fetched via L3/fabric by all 8.
__global__ __launch_bounds__(256) void sample_kernel(const u16* __restrict__ val,
                                                     const u16* __restrict__ awb,
                                                     u16* __restrict__ out) {
    int bid = blockIdx.x;
    int nb = gridDim.x;
    if ((nb & 7) == 0) { int q8 = nb >> 3; bid = (bid & 7) * q8 + (bid >> 3); }
    int tid = bid * 256 + threadIdx.x;
    int ch = tid & 1;             // hd half (16 elems)
    int pair = tid >> 1;          // l*NH + n
    int n = pair & 7;
    int l = pair >> 3;
    int iy = l >> 7, ix = l & 127;
    float cx = (ix + 0.5f) * (1.f / 128.f);
    float cy = (iy + 0.5f) * (1.f / 128.f);
    const u16* rowp = awb + (size_t)l * 256;
    const u16* o = rowp + 200 + n * 4;
    float bx = cx + bf2f(o[0]) * (0.025f / 8.f);
    float by = cy + bf2f(o[1]) * (0.025f / 8.f);
    float bw = 0.025f + bf2f(o[2]) * (0.025f / 8.f);
    float bh = 0.025f + bf2f(o[3]) * (0.025f / 8.f);
    const u16* awp = rowp + n * 25;   // RAW scores — softmax applied inline below
    const u16* vbase = val + n * 32 + ch * 16;

    // softmax stats (f32, no bf16 round-trip on the weights)
    float mx = -1e30f;
    for (int k = 0; k < 25; k++) mx = fmaxf(mx, bf2f(awp[k]));
    float s = 0.f;
    for (int k = 0; k < 25; k++) s += __expf(bf2f(awp[k]) - mx);
    float inv = 1.f / s;

    float acc0[8] = {}, acc1[8] = {};
    for (int k = 0; k < 25; k++) {
        float gx = (float)(k % 5 - 2) * 0.25f;
        float gy = (float)(k / 5 - 2) * 0.25f;
        float xx = (bx + bw * gx) * 128.f - 0.5f;
        float yy = (by + bh * gy) * 128.f - 0.5f;
        float x0 = floorf(xx), y0 = floorf(yy);
        float a_ = __expf(bf2f(awp[k]) - mx) * inv;
#pragma unroll
        for (int dy = 0; dy < 2; dy++) {
#pragma unroll
            for (int dx = 0; dx < 2; dx++) {
                float xi = x0 + dx, yi = y0 + dy;
                float w_ = (1.f - fabsf(xx - xi)) * (1.f - fabsf(yy - yi)) * a_;
                bool valid = (xi >= 0.f) & (xi < 128.f) & (yi >= 0.f) & (yi < 128.f);
                w_ = valid ? w_ : 0.f;
                int ixi = min(max((int)xi, 0), 127);
                int iyi = min(max((int)yi, 0), 127);
                int idx = iyi * 128 + ixi;
                const u16* p = vbase + (size_t)idx * 256;
                bf16x8 va = *(const bf16x8*)(p);
                bf16x8 vb = *(const bf16x8*)(p + 8);
#pragma unroll
                for (int e = 0; e < 8; e++) {
                    acc0[e] += w_ * bf2f((u16)va[e]);
                    acc1[e] += w_ * bf2f((u16)vb[e]);
                }
            }
        }
    }
    bf16x8 ov0, ov1;
#pragma unroll
    for (int e = 0; e < 8; e++) {
        ov0[e] = (short)f2bf(acc0[e]);
        ov1[e] = (short)f2bf(acc1[e]);
    }
    u16* op = out + (size_t)l * 256 + n * 32 + ch * 16;
    *(bf16x8*)(op) = ov0;
    *(bf16x8*)(op + 8) = ov1;
}

// ---------------- LayerNorm: one row per wave, fully in registers ----------------
__global__ __launch_bounds__(256) void ln_rows_bf16(const u16* __restrict__ xin,
                                                    const u16* __restrict__ delta,
                                                    const float* __restrict__ g,
                                                    const float* __restrict__ b,
                                                    u16* __restrict__ out) {
    int lane = threadIdx.x & 63;
    int row = blockIdx.x * 4 + (threadIdx.x >> 6);
    size_t base = (size_t)row * 256 + lane * 4;
    u16x4 xv = *(const u16x4*)(xin + base);
    u16x4 dv = *(const u16x4*)(delta + base);
    float v[4]; float s = 0.f, q = 0.f;
#pragma unroll
    for (int j = 0; j < 4; j++) {
        v[j] = bf2f(xv[j]) + bf2f(dv[j]);
        s += v[j]; q += v[j] * v[j];
    }
#pragma unroll
    for (int off = 1; off < 64; off <<= 1) {
        s += __shfl_xor(s, off, 64);
        q += __shfl_xor(q, off, 64);
    }
    float m = s * (1.f / 256.f);
    float var = q * (1.f / 256.f) - m * m;
    float r = rsqrtf(var + 1e-5f);
    f32x4 gv = *(const f32x4*)(g + lane * 4);
    f32x4 bv2 = *(const f32x4*)(b + lane * 4);
    u16x4 ov;
#pragma unroll
    for (int j = 0; j < 4; j++)
        ov[j] = f2bf((v[j] - m) * r * gv[j] + bv2[j]);
    *(u16x4*)(out + base) = ov;
}

// final LN writes FLOAT32 — d_out is the reference's output dtype (f32)
__global__ __launch_bounds__(256) void ln_rows_f32(const u16* __restrict__ xin,
                                                   const u16* __restrict__ delta,
                                                   const float* __restrict__ g,
                                                   const float* __restrict__ b,
                                                   float* __restrict__ out) {
    int lane = threadIdx.x & 63;
    int row = blockIdx.x * 4 + (threadIdx.x >> 6);
    size_t base = (size_t)row * 256 + lane * 4;
    u16x4 xv = *(const u16x4*)(xin + base);
    u16x4 dv = *(const u16x4*)(delta + base);
    float v[4]; float s = 0.f, q = 0.f;
#pragma unroll
    for (int j = 0; j < 4; j++) {
        v[j] = bf2f(xv[j]) + bf2f(dv[j]);
        s += v[j]; q += v[j] * v[j];
    }
#pragma unroll
    for (int off = 1; off < 64; off <<= 1) {
        s += __shfl_xor(s, off, 64);
        q += __shfl_xor(q, off, 64);
    }
    float m = s * (1.f / 256.f);
    float var = q * (1.f / 256.f) - m * m;
    float r = rsqrtf(var + 1e-5f);
    f32x4 gv = *(const f32x4*)(g + lane * 4);
    f32x4 bv2 = *(const f32x4*)(b + lane * 4);
    f32x4 ov;
#pragma unroll
    for (int j = 0; j < 4; j++)
        ov[j] = (v[j] - m) * r * gv[j] + bv2[j];
    *(f32x4*)(out + base) = ov;
}

extern "C" void kernel_launch(void* const* d_in, const int* in_sizes, int n_in,
                              void* d_out, int out_size, void* d_ws, size_t ws_size,
                              hipStream_t stream) {
    const size_t MiB = 1048576;
    float* outp = (float*)d_out;
    int fillg = (out_size + 255) / 256;

    // ---- environment sentinels ----
    const int exp_sizes[18] = {4194304, 4194304, 131072, 512, 16384, 64, 102400, 400,
                               131072, 512, 524288, 2048, 524288, 512, 512, 512, 512, 512};
    bool env_ok = (n_in == 18) && (ws_size >= 25 * MiB) && (out_size == 4194304);
    if (env_ok) for (int i = 0; i < 18; i++) env_ok = env_ok && (in_sizes[i] == exp_sizes[i]);
    if (!env_ok) {
        hipLaunchKernelGGL(fill_kernel, dim3(fillg), dim3(256), 0, stream, outp, out_size, 3000.f);
        return;
    }

    const float* srcp  = (const float*)d_in[0];
    const float* posp  = (const float*)d_in[1];
    const float* Wv    = (const float*)d_in[2];
    const float* bv    = (const float*)d_in[3];
    const float* Wbox  = (const float*)d_in[4];
    const float* bbox  = (const float*)d_in[5];
    const float* Wattn = (const float*)d_in[6];
    const float* battn = (const float*)d_in[7];
    const float* Wo    = (const float*)d_in[8];
    const float* bo    = (const float*)d_in[9];
    const float* W1    = (const float*)d_in[10];
    const float* b1    = (const float*)d_in[11];
    const float* W2    = (const float*)d_in[12];
    const float* b2    = (const float*)d_in[13];
    const float* ln1g  = (const float*)d_in[14];
    const float* ln1b  = (const float*)d_in[15];
    const float* ln2g  = (const float*)d_in[16];
    const float* ln2b  = (const float*)d_in[17];

    char* ws = (char*)d_ws;
    // ws:   [0,8) x    [8,16) val / hiddenA    [16,24) awb / tmp / ffnout
    // dout: [0,8) q -> attn -> hiddenB (sequential liveness)   [8,~13.6) wbuf
    u16* x       = (u16*)(ws + 0);
    u16* val     = (u16*)(ws + 8 * MiB);
    u16* hiddenA = (u16*)(ws + 8 * MiB);
    u16* awb     = (u16*)(ws + 16 * MiB);
    u16* tmp     = (u16*)(ws + 16 * MiB);
    u16* ffnout  = (u16*)(ws + 16 * MiB);
    u16* q       = (u16*)d_out;
    u16* attn    = (u16*)d_out;
    u16* hiddenB = (u16*)d_out;
    u16* wbuf    = (u16*)((char*)d_out + 8 * MiB);
    const size_t LSTR = 1474560;  // u16 elems per layer of packed weights

    const int ND = L_TOK * DMODEL;
    const int BIG = 1 << 20;

    auto GD128 = [&](const u16* Aa, const u16* Bha, const float* ba_, u16* Ca,
                     const u16* Ab, const u16* Bhb, const float* bb_, u16* Cb,
                     int gx, int gy, int K, int ldC, int relu, int ysplit) {
        hipLaunchKernelGGL((gemm_dual<128>), dim3(gx, gy), dim3(256), 0, stream,
                           Aa, Bha, ba_, Ca, Ab, Bhb, bb_, Cb, K, ldC, relu, ysplit);
    };
    auto GD64 = [&](const u16* Aa, const u16* Bha, const float* ba_, u16* Ca,
                    const u16* Ab, const u16* Bhb, const float* bb_, u16* Cb,
                    int gx, int gy, int K, int ldC, int relu, int ysplit) {
        hipLaunchKernelGGL((gemm_dual<64>), dim3(gx, gy), dim3(256), 0, stream,
                           Aa, Bha, ba_, Ca, Ab, Bhb, bb_, Cb, K, ldC, relu, ysplit);
    };

    // ---- prepack ALL weights (both layers) in ONE dispatch (hi-only) ----
    hipLaunchKernelGGL(prepack_all, dim3((2 * 720896 + 255) / 256), dim3(256), 0, stream,
                       Wattn, Wbox, battn, bbox, Wv, Wo, W1, W2, wbuf);

    // x = src^T  (tiled, coalesced both sides)
    hipLaunchKernelGGL(xpose_tiled, dim3(4, 256), dim3(256), 0, stream, srcp, x);

    for (int i = 0; i < 2; i++) {
        u16* wb = wbuf + (size_t)i * LSTR;

        hipLaunchKernelGGL(addq_tiled, dim3(4, 256), dim3(256), 0, stream, x, posp, q);

        // merged: comb(q->awb) + Wv(x->val) in one dispatch (grid 4 x 256, ysplit 128)
        GD128(q, wb + 0,      (const float*)(wb + 131072), awb,
              x, wb + 163840, bv + (size_t)i * 256,        val,
              4, 256, 256, 256, 0, 128);

        // sample with FUSED softmax (awb holds raw scores); 16-wide threads + XCD swizzle
        hipLaunchKernelGGL(sample_kernel, dim3(L_TOK * NHEAD * 2 / 256), dim3(256), 0, stream,
                           val, awb, attn);

        // Wo (single problem via dual kernel)
        GD128(attn, wb + 294912, bo + (size_t)i * 256, tmp,
              attn, wb + 294912, bo + (size_t)i * 256, tmp,
              4, 128, 256, 256, 0, BIG);

        hipLaunchKernelGGL(ln_rows_bf16, dim3(L_TOK / 4), dim3(256), 0, stream,
                           x, tmp, ln1g + (size_t)i * 256, ln1b + (size_t)i * 256, x);

        // FFN over two half-passes; each half = 8192 rows split across hiddenA/hiddenB
        for (int c = 0; c < 2; c++) {
            const u16* xa = x + (size_t)c * 8192 * 256;
            u16* ya = ffnout + (size_t)c * 8192 * 256;
            GD128(xa,                      wb + 425984, b1 + (size_t)i * 1024, hiddenA,
                  xa + (size_t)4096 * 256, wb + 425984, b1 + (size_t)i * 1024, hiddenB,
                  16, 64, 256, 1024, 1, 32);
            GD64(hiddenA, wb + 950272, b2 + (size_t)i * 256, ya,
                 hiddenB, wb + 950272, b2 + (size_t)i * 256, ya + (size_t)4096 * 256,
                 4, 128, 1024, 256, 0, 64);
        }

        if (i == 0) {
            hipLaunchKernelGGL(ln_rows_bf16, dim3(L_TOK / 4), dim3(256), 0, stream,
                               x, ffnout, ln2g, ln2b, x);
        } else {
            // FINAL: float32 output
            hipLaunchKernelGGL(ln_rows_f32, dim3(L_TOK / 4), dim3(256), 0, stream,
                               x, ffnout, ln2g + 256, ln2b + 256, outp);
        }
    }
}